// Round 2
// baseline (1336.884 us; speedup 1.0000x reference)
//
#include <hip/hip_runtime.h>
#include <hip/hip_bf16.h>

// Shapes (fixed by the reference)
#define BB   4
#define NN   2048
#define FIN  128
#define HD   256
#define NH   4
#define DK   64
#define NEGV (-1000000000.0f)

// ---------------------------------------------------------------------------
// K1: x[b,n,c] = sum_i nf[b,n,i]*Wp[i,c] + bp[c]         (f32 out)
// one block per (b,n), 256 threads = one output channel each
__global__ void __launch_bounds__(256) k_proj(const float* __restrict__ nf,
                                              const float* __restrict__ Wp,
                                              const float* __restrict__ bp,
                                              float* __restrict__ x){
  int bn = blockIdx.x; int c = threadIdx.x;
  __shared__ float xs[FIN];
  if (c < FIN) xs[c] = nf[bn*FIN + c];
  __syncthreads();
  float acc = bp[c];
  #pragma unroll 8
  for (int i = 0; i < FIN; ++i) acc = fmaf(xs[i], Wp[i*HD + c], acc);
  x[bn*HD + c] = acc;
}

// ---------------------------------------------------------------------------
// K2: per head: h[b,hh,n,d] = sum_i x[b,n,i]*W[hh,i,d];
//     src[b,hh,n] = sum_d h*a_src[hh,d]; dst likewise (wave reduce, lane0 writes)
// block = 256 threads = 4 waves; wave w handles row n = tile*4+w, lane = d
__global__ void __launch_bounds__(256) k_head(const float* __restrict__ x,
                                              const float* __restrict__ W,
                                              const float* __restrict__ a,
                                              float* __restrict__ h,
                                              float* __restrict__ src,
                                              float* __restrict__ dst){
  int tile = blockIdx.x;
  int nt = tile & (NN/4 - 1);
  int bh = tile / (NN/4);           // b*NH + hh
  int b  = bh >> 2; int hh = bh & 3;
  int w = threadIdx.x >> 6; int d = threadIdx.x & 63;
  __shared__ float xs[4][HD];
  for (int k = threadIdx.x; k < 4*HD; k += 256){
    int r = k >> 8; int cc = k & 255;
    xs[r][cc] = x[(b*NN + nt*4 + r)*HD + cc];
  }
  __syncthreads();
  const float* Wh = W + hh*HD*DK;
  float acc = 0.f;
  #pragma unroll 8
  for (int i = 0; i < HD; ++i) acc = fmaf(xs[w][i], Wh[i*DK + d], acc);
  int n = nt*4 + w;
  h[(size_t)(bh*NN + n)*DK + d] = acc;
  float s = acc * a[hh*2*DK + d];
  float t = acc * a[hh*2*DK + DK + d];
  #pragma unroll
  for (int o = 32; o >= 1; o >>= 1){ s += __shfl_xor(s, o); t += __shfl_xor(t, o); }
  if (d == 0){ src[bh*NN + n] = s; dst[bh*NN + n] = t; }
}

// ---------------------------------------------------------------------------
// K3: attention row. block per (b,hh,n).
//   e_m = adj ? leaky(src_n + dst_m) : NEG ; p = softmax(e) ; out_d = sum_m p_m h[m,d]
__global__ void __launch_bounds__(256) k_attn(const float* __restrict__ h,
                                              const float* __restrict__ src,
                                              const float* __restrict__ dst,
                                              const int* __restrict__ adj,
                                              float* __restrict__ out){
  int n  = blockIdx.x & (NN-1);
  int bh = blockIdx.x / NN;
  int b  = bh >> 2;
  int t  = threadIdx.x;
  __shared__ float p[NN];       // 8 KB
  __shared__ float red[256];
  __shared__ float acc4[4][DK];
  float sn = src[bh*NN + n];
  const float* dr = dst + bh*NN;
  const int*  ar = adj + (size_t)(b*NN + n)*NN;
  float mx = -INFINITY;
  for (int m = t; m < NN; m += 256){
    float e = sn + dr[m];
    e = (e >= 0.f) ? e : 0.2f*e;       // leaky_relu THEN mask (reference order)
    e = (ar[m] == 0) ? NEGV : e;
    p[m] = e;
    mx = fmaxf(mx, e);
  }
  red[t] = mx; __syncthreads();
  for (int o = 128; o >= 1; o >>= 1){ if (t < o) red[t] = fmaxf(red[t], red[t+o]); __syncthreads(); }
  mx = red[0]; __syncthreads();
  float sum = 0.f;
  for (int m = t; m < NN; m += 256){ float e = __expf(p[m] - mx); p[m] = e; sum += e; }
  red[t] = sum; __syncthreads();
  for (int o = 128; o >= 1; o >>= 1){ if (t < o) red[t] += red[t+o]; __syncthreads(); }
  float inv = 1.f / red[0];
  __syncthreads();
  // PV: lane d, 4 m-chunks of 512
  int d = t & 63; int ch = t >> 6;
  const float* hb = h + (size_t)bh*NN*DK;
  float acc = 0.f;
  for (int m = ch*(NN/4); m < (ch+1)*(NN/4); ++m)
    acc = fmaf(p[m], hb[m*DK + d], acc);
  acc4[ch][d] = acc; __syncthreads();
  if (ch == 0)
    out[(size_t)(bh*NN + n)*DK + d] = (acc4[0][d] + acc4[1][d] + acc4[2][d] + acc4[3][d]) * inv;
}

// ---------------------------------------------------------------------------
// K4: x[b,j,:] += elu(LN(x1[b,j,:]))  where x1 is the RESHAPE-REINTERPRET of att1:
//   x1[b, j, c] = att[b, hh=j>>9, node=4*(j&511)+(c>>6), d=c&63]
__global__ void __launch_bounds__(256) k_ln1(const float* __restrict__ att,
                                             const float* __restrict__ sc,
                                             const float* __restrict__ bi,
                                             float* __restrict__ x){
  int j = blockIdx.x & (NN-1);
  int b = blockIdx.x / NN;
  int c = threadIdx.x;
  int hh = j >> 9;
  int node = ((j & 511) << 2) + (c >> 6);
  int d = c & 63;
  float v = att[(((size_t)(b*NH + hh)*NN) + node)*DK + d];
  __shared__ float red[256];
  red[c] = v; __syncthreads();
  for (int o = 128; o >= 1; o >>= 1){ if (c < o) red[c] += red[c+o]; __syncthreads(); }
  float mu = red[0] * (1.f/HD); __syncthreads();
  float dv = v - mu;
  red[c] = dv*dv; __syncthreads();
  for (int o = 128; o >= 1; o >>= 1){ if (c < o) red[c] += red[c+o]; __syncthreads(); }
  float var = red[0] * (1.f/HD);
  float ln = dv * rsqrtf(var + 1e-5f) * sc[c] + bi[c];
  float el = (ln > 0.f) ? ln : (__expf(ln) - 1.f);   // elu, alpha=1
  x[(size_t)blockIdx.x*HD + c] += el;
}

// ---------------------------------------------------------------------------
// K5: out[b,n,d] = LN_64( mean_h att2[b,h,n,d] ) -> f32
// 256 threads = 4 waves, one row per wave
__global__ void __launch_bounds__(256) k_final(const float* __restrict__ att,
                                               const float* __restrict__ sc,
                                               const float* __restrict__ bi,
                                               float* __restrict__ out){
  int w = threadIdx.x >> 6; int d = threadIdx.x & 63;
  int bn = blockIdx.x*4 + w;
  int b = bn / NN; int n = bn & (NN-1);
  float v = 0.f;
  #pragma unroll
  for (int hh = 0; hh < NH; ++hh) v += att[((size_t)(b*NH + hh)*NN + n)*DK + d];
  v *= 0.25f;
  float s = v;
  #pragma unroll
  for (int o = 32; o >= 1; o >>= 1) s += __shfl_xor(s, o);
  float mu = s * (1.f/DK);
  float dv = v - mu;
  float q = dv*dv;
  #pragma unroll
  for (int o = 32; o >= 1; o >>= 1) q += __shfl_xor(q, o);
  float var = q * (1.f/DK);
  float ln = dv * rsqrtf(var + 1e-5f) * sc[d] + bi[d];
  out[(size_t)bn*DK + d] = ln;
}

// ---------------------------------------------------------------------------
extern "C" void kernel_launch(void* const* d_in, const int* in_sizes, int n_in,
                              void* d_out, int out_size, void* d_ws, size_t ws_size,
                              hipStream_t stream){
  const float* nf   = (const float*)d_in[0];
  const int*   adj  = (const int*)d_in[1];
  const float* Wp   = (const float*)d_in[2];
  const float* bp   = (const float*)d_in[3];
  const float* W1   = (const float*)d_in[4];
  const float* a1   = (const float*)d_in[5];
  const float* ln1s = (const float*)d_in[6];
  const float* ln1b = (const float*)d_in[7];
  const float* W2   = (const float*)d_in[8];
  const float* a2   = (const float*)d_in[9];
  const float* ln2s = (const float*)d_in[10];
  const float* ln2b = (const float*)d_in[11];

  float* ws  = (float*)d_ws;
  float* x   = ws;                 // B*N*HID      = 2,097,152 f32
  float* h   = ws +   2097152;     // B*H*N*DK     = 2,097,152 f32
  float* att = ws + 2*2097152;     // B*H*N*DK     = 2,097,152 f32
  float* src = ws + 3*2097152;     // B*H*N        =    32,768 f32
  float* dst = src + 32768;

  k_proj <<<BB*NN,        256, 0, stream>>>(nf, Wp, bp, x);
  k_head <<<BB*NH*NN/4,   256, 0, stream>>>(x, W1, a1, h, src, dst);
  k_attn <<<BB*NH*NN,     256, 0, stream>>>(h, src, dst, adj, att);
  k_ln1  <<<BB*NN,        256, 0, stream>>>(att, ln1s, ln1b, x);
  k_head <<<BB*NH*NN/4,   256, 0, stream>>>(x, W2, a2, h, src, dst);
  k_attn <<<BB*NH*NN,     256, 0, stream>>>(h, src, dst, adj, att);
  k_final<<<BB*NN/4,      256, 0, stream>>>(att, ln2s, ln2b, (float*)d_out);
}

// Round 3
// 762.449 us; speedup vs baseline: 1.7534x; 1.7534x over previous
//
#include <hip/hip_runtime.h>
#include <hip/hip_bf16.h>

// Shapes (fixed by the reference)
#define BB   4
#define NN   2048
#define FIN  128
#define HD   256
#define NH   4
#define DK   64
#define NEGV (-1000000000.0f)
#define RT   32      // rows per attention block
#define MT   64      // m-tile (cols per stage)

// ---------------------------------------------------------------------------
// K1: x[b,n,c] = sum_i nf[b,n,i]*Wp[i,c] + bp[c]
__global__ void __launch_bounds__(256) k_proj(const float* __restrict__ nf,
                                              const float* __restrict__ Wp,
                                              const float* __restrict__ bp,
                                              float* __restrict__ x){
  int bn = blockIdx.x; int c = threadIdx.x;
  __shared__ float xs[FIN];
  if (c < FIN) xs[c] = nf[bn*FIN + c];
  __syncthreads();
  float acc = bp[c];
  #pragma unroll 8
  for (int i = 0; i < FIN; ++i) acc = fmaf(xs[i], Wp[i*HD + c], acc);
  x[bn*HD + c] = acc;
}

// ---------------------------------------------------------------------------
// K2: h[b,hh,n,d] = sum_i x[b,n,i]*W[hh,i,d]; src/dst = dot(h, a_src/a_dst)
__global__ void __launch_bounds__(256) k_head(const float* __restrict__ x,
                                              const float* __restrict__ W,
                                              const float* __restrict__ a,
                                              float* __restrict__ h,
                                              float* __restrict__ src,
                                              float* __restrict__ dst){
  int tile = blockIdx.x;
  int nt = tile & (NN/4 - 1);
  int bh = tile / (NN/4);
  int b  = bh >> 2; int hh = bh & 3;
  int w = threadIdx.x >> 6; int d = threadIdx.x & 63;
  __shared__ float xs[4][HD];
  for (int k = threadIdx.x; k < 4*HD; k += 256){
    int r = k >> 8; int cc = k & 255;
    xs[r][cc] = x[(b*NN + nt*4 + r)*HD + cc];
  }
  __syncthreads();
  const float* Wh = W + hh*HD*DK;
  float acc = 0.f;
  #pragma unroll 8
  for (int i = 0; i < HD; ++i) acc = fmaf(xs[w][i], Wh[i*DK + d], acc);
  int n = nt*4 + w;
  h[(size_t)(bh*NN + n)*DK + d] = acc;
  float s = acc * a[hh*2*DK + d];
  float t = acc * a[hh*2*DK + DK + d];
  #pragma unroll
  for (int o = 32; o >= 1; o >>= 1){ s += __shfl_xor(s, o); t += __shfl_xor(t, o); }
  if (d == 0){ src[bh*NN + n] = s; dst[bh*NN + n] = t; }
}

// ---------------------------------------------------------------------------
// K2b: Mx[bh] = max_m dst[bh, m]   (16 blocks)
__global__ void __launch_bounds__(256) k_dmax(const float* __restrict__ dst,
                                              float* __restrict__ Mx){
  int bh = blockIdx.x; int t = threadIdx.x;
  float m = -INFINITY;
  for (int i = t; i < NN; i += 256) m = fmaxf(m, dst[bh*NN + i]);
  __shared__ float red[256];
  red[t] = m; __syncthreads();
  for (int o = 128; o >= 1; o >>= 1){ if (t < o) red[t] = fmaxf(red[t], red[t+o]); __syncthreads(); }
  if (t == 0) Mx[bh] = red[0];
}

// ---------------------------------------------------------------------------
// K3: tiled attention. Block = 32 rows of one (b,hh). 4 waves x 8 rows.
// Upper-bound max trick: bnd_n = leaky(src_n + max_m dst_m) >= all scores.
// p = exp(e - bnd); denom accumulated lane-locally, reduced once at end.
__global__ void __launch_bounds__(256) k_attn2(const float* __restrict__ h,
                                               const float* __restrict__ src,
                                               const float* __restrict__ dst,
                                               const float* __restrict__ Mx,
                                               const int* __restrict__ adj,
                                               float* __restrict__ out){
  int rt = blockIdx.x & (NN/RT - 1);
  int bh = blockIdx.x / (NN/RT);
  int b  = bh >> 2;
  int n0 = rt*RT;
  int w = threadIdx.x >> 6; int lane = threadIdx.x & 63;

  __shared__ float h_t[DK][MT+1];      // transposed h tile: h_t[d][m]
  __shared__ float dst_t[MT];
  __shared__ float p_s[4][8][MT];      // per-wave p rows

  const float* hb = h + (size_t)bh*NN*DK;
  const float* dr = dst + bh*NN;
  float Mbh = Mx[bh];

  float acc[8], psum[8], bnd[8];
  const int* arow[8];
  #pragma unroll
  for (int j = 0; j < 8; ++j){
    int n = n0 + w*8 + j;
    float s = src[bh*NN + n];
    float bv = s + Mbh;
    bnd[j] = (bv >= 0.f) ? bv : 0.2f*bv;
    acc[j] = 0.f; psum[j] = 0.f;
    arow[j] = adj + (size_t)(b*NN + n)*NN;
  }

  for (int t = 0; t < NN/MT; ++t){
    int m0 = t*MT;
    __syncthreads();                       // prev PV done before restage
    for (int k = threadIdx.x; k < MT*DK; k += 256){
      int mloc = k >> 6, d = k & 63;
      h_t[d][mloc] = hb[(size_t)(m0 + mloc)*DK + d];
    }
    if (threadIdx.x < MT) dst_t[threadIdx.x] = dr[m0 + threadIdx.x];
    __syncthreads();

    // score phase (per-wave, lane = m)
    float dv = dst_t[lane];
    #pragma unroll
    for (int j = 0; j < 8; ++j){
      float e = src[bh*NN + n0 + w*8 + j];  // cached; cheap
      e = e + dv;
      e = (e >= 0.f) ? e : 0.2f*e;
      int av = arow[j][m0 + lane];
      e = av ? e : NEGV;
      float p = __expf(e - bnd[j]);
      psum[j] += p;
      p_s[w][j][lane] = p;
    }

    // PV phase (per-wave, lane = d), register-blocked over 8 rows
    #pragma unroll 4
    for (int g = 0; g < MT/4; ++g){
      int mb = g*4;
      float h0 = h_t[lane][mb+0];
      float h1 = h_t[lane][mb+1];
      float h2 = h_t[lane][mb+2];
      float h3 = h_t[lane][mb+3];
      #pragma unroll
      for (int j = 0; j < 8; ++j){
        float4 pb = *(const float4*)&p_s[w][j][mb];   // broadcast
        acc[j] = fmaf(pb.x, h0, acc[j]);
        acc[j] = fmaf(pb.y, h1, acc[j]);
        acc[j] = fmaf(pb.z, h2, acc[j]);
        acc[j] = fmaf(pb.w, h3, acc[j]);
      }
    }
  }

  // final denominator reduce + write
  #pragma unroll
  for (int j = 0; j < 8; ++j){
    float s = psum[j];
    #pragma unroll
    for (int o = 32; o >= 1; o >>= 1) s += __shfl_xor(s, o);
    int n = n0 + w*8 + j;
    out[(size_t)(bh*NN + n)*DK + lane] = acc[j] / s;
  }
}

// ---------------------------------------------------------------------------
// K4: x[b,j,:] += elu(LN(x1[b,j,:])), x1 = reshape-reinterpret of att1
__global__ void __launch_bounds__(256) k_ln1(const float* __restrict__ att,
                                             const float* __restrict__ sc,
                                             const float* __restrict__ bi,
                                             float* __restrict__ x){
  int j = blockIdx.x & (NN-1);
  int b = blockIdx.x / NN;
  int c = threadIdx.x;
  int hh = j >> 9;
  int node = ((j & 511) << 2) + (c >> 6);
  int d = c & 63;
  float v = att[(((size_t)(b*NH + hh)*NN) + node)*DK + d];
  __shared__ float red[256];
  red[c] = v; __syncthreads();
  for (int o = 128; o >= 1; o >>= 1){ if (c < o) red[c] += red[c+o]; __syncthreads(); }
  float mu = red[0] * (1.f/HD); __syncthreads();
  float dv = v - mu;
  red[c] = dv*dv; __syncthreads();
  for (int o = 128; o >= 1; o >>= 1){ if (c < o) red[c] += red[c+o]; __syncthreads(); }
  float var = red[0] * (1.f/HD);
  float ln = dv * rsqrtf(var + 1e-5f) * sc[c] + bi[c];
  float el = (ln > 0.f) ? ln : (__expf(ln) - 1.f);
  x[(size_t)blockIdx.x*HD + c] += el;
}

// ---------------------------------------------------------------------------
// K5: out[b,n,d] = LN_64( mean_h att2[b,h,n,d] )
__global__ void __launch_bounds__(256) k_final(const float* __restrict__ att,
                                               const float* __restrict__ sc,
                                               const float* __restrict__ bi,
                                               float* __restrict__ out){
  int w = threadIdx.x >> 6; int d = threadIdx.x & 63;
  int bn = blockIdx.x*4 + w;
  int b = bn / NN; int n = bn & (NN-1);
  float v = 0.f;
  #pragma unroll
  for (int hh = 0; hh < NH; ++hh) v += att[((size_t)(b*NH + hh)*NN + n)*DK + d];
  v *= 0.25f;
  float s = v;
  #pragma unroll
  for (int o = 32; o >= 1; o >>= 1) s += __shfl_xor(s, o);
  float mu = s * (1.f/DK);
  float dv = v - mu;
  float q = dv*dv;
  #pragma unroll
  for (int o = 32; o >= 1; o >>= 1) q += __shfl_xor(q, o);
  float var = q * (1.f/DK);
  float ln = dv * rsqrtf(var + 1e-5f) * sc[d] + bi[d];
  out[(size_t)bn*DK + d] = ln;
}

// ---------------------------------------------------------------------------
extern "C" void kernel_launch(void* const* d_in, const int* in_sizes, int n_in,
                              void* d_out, int out_size, void* d_ws, size_t ws_size,
                              hipStream_t stream){
  const float* nf   = (const float*)d_in[0];
  const int*   adj  = (const int*)d_in[1];
  const float* Wp   = (const float*)d_in[2];
  const float* bp   = (const float*)d_in[3];
  const float* W1   = (const float*)d_in[4];
  const float* a1   = (const float*)d_in[5];
  const float* ln1s = (const float*)d_in[6];
  const float* ln1b = (const float*)d_in[7];
  const float* W2   = (const float*)d_in[8];
  const float* a2   = (const float*)d_in[9];
  const float* ln2s = (const float*)d_in[10];
  const float* ln2b = (const float*)d_in[11];

  float* ws  = (float*)d_ws;
  float* x   = ws;                 // B*N*HID   = 2,097,152 f32
  float* h   = ws +   2097152;     // B*H*N*DK  = 2,097,152 f32
  float* att = ws + 2*2097152;     // B*H*N*DK  = 2,097,152 f32
  float* src = ws + 3*2097152;     // 32,768 f32
  float* dst = src + 32768;        // 32,768 f32
  float* Mx  = dst + 32768;        // 16 f32

  k_proj <<<BB*NN,           256, 0, stream>>>(nf, Wp, bp, x);
  k_head <<<BB*NH*NN/4,      256, 0, stream>>>(x, W1, a1, h, src, dst);
  k_dmax <<<BB*NH,           256, 0, stream>>>(dst, Mx);
  k_attn2<<<BB*NH*NN/RT,     256, 0, stream>>>(h, src, dst, Mx, adj, att);
  k_ln1  <<<BB*NN,           256, 0, stream>>>(att, ln1s, ln1b, x);
  k_head <<<BB*NH*NN/4,      256, 0, stream>>>(x, W2, a2, h, src, dst);
  k_dmax <<<BB*NH,           256, 0, stream>>>(dst, Mx);
  k_attn2<<<BB*NH*NN/RT,     256, 0, stream>>>(h, src, dst, Mx, adj, att);
  k_final<<<BB*NN/4,         256, 0, stream>>>(att, ln2s, ln2b, (float*)d_out);
}

// Round 4
// 342.200 us; speedup vs baseline: 3.9067x; 2.2281x over previous
//
#include <hip/hip_runtime.h>
#include <hip/hip_bf16.h>
#include <hip/hip_fp16.h>

// Shapes (fixed by the reference)
#define BB   4
#define NN   2048
#define FIN  128
#define HD   256
#define NH   4
#define DK   64
#define NEGV (-1000000000.0f)

typedef _Float16 f16x8 __attribute__((ext_vector_type(8)));
typedef float    f32x16 __attribute__((ext_vector_type(16)));

// XOR swizzle: flip byte bits 4-6 with row bits (row = byte>>7, 128B rows)
__device__ __forceinline__ int SWZ(int b){ return b ^ (((b >> 7) & 7) << 4); }

// ---------------------------------------------------------------------------
// K1: x[b,n,c] = sum_i nf[b,n,i]*Wp[i,c] + bp[c]
__global__ void __launch_bounds__(256) k_proj(const float* __restrict__ nf,
                                              const float* __restrict__ Wp,
                                              const float* __restrict__ bp,
                                              float* __restrict__ x){
  int bn = blockIdx.x; int c = threadIdx.x;
  __shared__ float xs[FIN];
  if (c < FIN) xs[c] = nf[bn*FIN + c];
  __syncthreads();
  float acc = bp[c];
  #pragma unroll 8
  for (int i = 0; i < FIN; ++i) acc = fmaf(xs[i], Wp[i*HD + c], acc);
  x[bn*HD + c] = acc;
}

// ---------------------------------------------------------------------------
// K2: h[b,hh,n,d] = sum_i x[b,n,i]*W[hh,i,d]; src/dst = dot(h, a_src/a_dst)
__global__ void __launch_bounds__(256) k_head(const float* __restrict__ x,
                                              const float* __restrict__ W,
                                              const float* __restrict__ a,
                                              float* __restrict__ h,
                                              float* __restrict__ src,
                                              float* __restrict__ dst){
  int tile = blockIdx.x;
  int nt = tile & (NN/4 - 1);
  int bh = tile / (NN/4);
  int b  = bh >> 2; int hh = bh & 3;
  int w = threadIdx.x >> 6; int d = threadIdx.x & 63;
  __shared__ float xs[4][HD];
  for (int k = threadIdx.x; k < 4*HD; k += 256){
    int r = k >> 8; int cc = k & 255;
    xs[r][cc] = x[(b*NN + nt*4 + r)*HD + cc];
  }
  __syncthreads();
  const float* Wh = W + hh*HD*DK;
  float acc = 0.f;
  #pragma unroll 8
  for (int i = 0; i < HD; ++i) acc = fmaf(xs[w][i], Wh[i*DK + d], acc);
  int n = nt*4 + w;
  h[(size_t)(bh*NN + n)*DK + d] = acc;
  float s = acc * a[hh*2*DK + d];
  float t = acc * a[hh*2*DK + DK + d];
  #pragma unroll
  for (int o = 32; o >= 1; o >>= 1){ s += __shfl_xor(s, o); t += __shfl_xor(t, o); }
  if (d == 0){ src[bh*NN + n] = s; dst[bh*NN + n] = t; }
}

// ---------------------------------------------------------------------------
// K2b: Mx[bh] = max_m dst[bh, m]
__global__ void __launch_bounds__(256) k_dmax(const float* __restrict__ dst,
                                              float* __restrict__ Mx){
  int bh = blockIdx.x; int t = threadIdx.x;
  float m = -INFINITY;
  for (int i = t; i < NN; i += 256) m = fmaxf(m, dst[bh*NN + i]);
  __shared__ float red[256];
  red[t] = m; __syncthreads();
  for (int o = 128; o >= 1; o >>= 1){ if (t < o) red[t] = fmaxf(red[t], red[t+o]); __syncthreads(); }
  if (t == 0) Mx[bh] = red[0];
}

// ---------------------------------------------------------------------------
// K2c: transpose+convert: hT_tiled[bh][mt][d][mloc] (f16) = h[bh][mt*64+mloc][d]
// grid = bh*32 (one 64-m tile each)
__global__ void __launch_bounds__(256) k_tr(const float* __restrict__ h,
                                            _Float16* __restrict__ hT){
  int mt = blockIdx.x & 31;
  int bh = blockIdx.x >> 5;
  int m0 = mt * 64;
  int t = threadIdx.x;
  __shared__ __align__(16) _Float16 lt[64][72];   // [d][m], 144B rows (16B aligned)
  #pragma unroll
  for (int k = 0; k < 4; ++k){
    int idx = k*256 + t;
    int m = idx >> 4;             // 0..63
    int d0 = (idx & 15) * 4;      // 0..60
    float4 v = *(const float4*)&h[(size_t)(bh*NN + m0 + m)*DK + d0];
    lt[d0+0][m] = (_Float16)v.x;
    lt[d0+1][m] = (_Float16)v.y;
    lt[d0+2][m] = (_Float16)v.z;
    lt[d0+3][m] = (_Float16)v.w;
  }
  __syncthreads();
  int d = t >> 2, seg = t & 3;
  f16x8 o0 = *(const f16x8*)&lt[d][seg*16];
  f16x8 o1 = *(const f16x8*)&lt[d][seg*16 + 8];
  _Float16* dstp = hT + (size_t)bh*DK*NN + mt*4096 + d*64 + seg*16;
  *(f16x8*)dstp = o0;
  *(f16x8*)(dstp + 8) = o1;
}

// ---------------------------------------------------------------------------
// K3: MFMA attention. Block = 128 rows of one (b,hh); 4 waves (2x2);
// BK = 64; A = P-tile (f16, LDS swizzled), B = hT-tile (f16, LDS swizzled).
// Bound-max softmax (no online max): bnd_n = leaky(src_n + max_m dst_m).
__global__ void __launch_bounds__(256) k_attn3(const float* __restrict__ src,
                                               const float* __restrict__ dst,
                                               const float* __restrict__ Mx,
                                               const _Float16* __restrict__ hT,
                                               const int* __restrict__ adj,
                                               float* __restrict__ out){
  int rb = blockIdx.x & 15;
  int bh = blockIdx.x >> 4;
  int b  = bh >> 2;
  int n0 = rb * 128;
  int t = threadIdx.x;
  int w = t >> 6, l = t & 63;
  int lh = l >> 5, l5 = l & 31;
  int wr = w >> 1, wc = w & 1;

  __shared__ __align__(16) char ps[2][128*128];  // P tile f16: [row 0..127][64 m] (128B rows)
  __shared__ __align__(16) char hs[2][64*128];   // hT tile f16: [d 0..63][64 m]
  __shared__ float rs[128];

  float Mbh = Mx[bh];
  float srcv[16], bnd[16], psum[16];
  #pragma unroll
  for (int q = 0; q < 16; ++q){
    int r = q*8 + w*2 + lh;
    float s = src[bh*NN + n0 + r];
    srcv[q] = s;
    float bv = s + Mbh;
    bnd[q] = (bv >= 0.f) ? bv : 0.2f*bv;
    psum[q] = 0.f;
  }
  f32x16 acc0 = {}; f32x16 acc1 = {};

  const _Float16* hTb = hT + (size_t)bh*DK*NN;
  int sd = t >> 2, sseg = t & 3;                 // staging role

  for (int mt = 0; mt < 32; ++mt){
    int cur = mt & 1;
    int m0 = mt * 64;

    // ---- stage hT tile (coalesced global read -> swizzled LDS write)
    const _Float16* gsrc = hTb + mt*4096 + sd*64 + sseg*16;
    f16x8 hv0 = *(const f16x8*)gsrc;
    f16x8 hv1 = *(const f16x8*)(gsrc + 8);
    int hb0 = sd*128 + sseg*32;
    *(f16x8*)&hs[cur][SWZ(hb0)]      = hv0;
    *(f16x8*)&hs[cur][SWZ(hb0 + 16)] = hv1;

    // ---- score phase: rows r = q*8 + w*2 + lh, m = m0 + 2*l5 (+1)
    float2 dm = *(const float2*)&dst[bh*NN + m0 + 2*l5];
    #pragma unroll
    for (int q = 0; q < 16; ++q){
      int r = q*8 + w*2 + lh;
      int n = n0 + r;
      const int2 av = *(const int2*)(adj + (size_t)(b*NN + n)*NN + m0 + 2*l5);
      float e0 = srcv[q] + dm.x;
      float e1 = srcv[q] + dm.y;
      e0 = (e0 >= 0.f) ? e0 : 0.2f*e0;
      e1 = (e1 >= 0.f) ? e1 : 0.2f*e1;
      e0 = av.x ? e0 : NEGV;
      e1 = av.y ? e1 : NEGV;
      float p0 = __expf(e0 - bnd[q]);
      float p1 = __expf(e1 - bnd[q]);
      psum[q] += p0 + p1;
      unsigned u = ((unsigned)__half_as_ushort(__float2half(p1)) << 16)
                 |  (unsigned)__half_as_ushort(__float2half(p0));
      *(unsigned*)&ps[cur][SWZ(r*128 + l5*4)] = u;
    }
    __syncthreads();

    // ---- MFMA phase: 2 row-subtiles x 4 k-steps
    #pragma unroll
    for (int kk = 0; kk < 4; ++kk){
      int co = kk*32 + lh*16;
      f16x8 A0 = *(const f16x8*)&ps[cur][SWZ((wr*64      + l5)*128 + co)];
      f16x8 A1 = *(const f16x8*)&ps[cur][SWZ((wr*64 + 32 + l5)*128 + co)];
      f16x8 Bv = *(const f16x8*)&hs[cur][SWZ((wc*32      + l5)*128 + co)];
      acc0 = __builtin_amdgcn_mfma_f32_32x32x16_f16(A0, Bv, acc0, 0, 0, 0);
      acc1 = __builtin_amdgcn_mfma_f32_32x32x16_f16(A1, Bv, acc1, 0, 0, 0);
    }
  }

  // ---- row sums -> LDS
  #pragma unroll
  for (int q = 0; q < 16; ++q){
    float s = psum[q];
    #pragma unroll
    for (int o = 16; o >= 1; o >>= 1) s += __shfl_xor(s, o);
    if (l5 == 0) rs[q*8 + w*2 + lh] = s;
  }
  __syncthreads();

  // ---- normalize + store (C layout: col=lane&31, row=(g&3)+8*(g>>2)+4*lh)
  #pragma unroll
  for (int g = 0; g < 16; ++g){
    int rbase = (g & 3) + 8*(g >> 2) + 4*lh;
    int col = wc*32 + l5;
    int row0 = wr*64 + rbase;
    int row1 = wr*64 + 32 + rbase;
    out[((size_t)bh*NN + n0 + row0)*DK + col] = acc0[g] / rs[row0];
    out[((size_t)bh*NN + n0 + row1)*DK + col] = acc1[g] / rs[row1];
  }
}

// ---------------------------------------------------------------------------
// K4: x[b,j,:] += elu(LN(x1[b,j,:])), x1 = reshape-reinterpret of att1
__global__ void __launch_bounds__(256) k_ln1(const float* __restrict__ att,
                                             const float* __restrict__ sc,
                                             const float* __restrict__ bi,
                                             float* __restrict__ x){
  int j = blockIdx.x & (NN-1);
  int b = blockIdx.x / NN;
  int c = threadIdx.x;
  int hh = j >> 9;
  int node = ((j & 511) << 2) + (c >> 6);
  int d = c & 63;
  float v = att[(((size_t)(b*NH + hh)*NN) + node)*DK + d];
  __shared__ float red[256];
  red[c] = v; __syncthreads();
  for (int o = 128; o >= 1; o >>= 1){ if (c < o) red[c] += red[c+o]; __syncthreads(); }
  float mu = red[0] * (1.f/HD); __syncthreads();
  float dv = v - mu;
  red[c] = dv*dv; __syncthreads();
  for (int o = 128; o >= 1; o >>= 1){ if (c < o) red[c] += red[c+o]; __syncthreads(); }
  float var = red[0] * (1.f/HD);
  float ln = dv * rsqrtf(var + 1e-5f) * sc[c] + bi[c];
  float el = (ln > 0.f) ? ln : (__expf(ln) - 1.f);
  x[(size_t)blockIdx.x*HD + c] += el;
}

// ---------------------------------------------------------------------------
// K5: out[b,n,d] = LN_64( mean_h att2[b,h,n,d] )
__global__ void __launch_bounds__(256) k_final(const float* __restrict__ att,
                                               const float* __restrict__ sc,
                                               const float* __restrict__ bi,
                                               float* __restrict__ out){
  int w = threadIdx.x >> 6; int d = threadIdx.x & 63;
  int bn = blockIdx.x*4 + w;
  int b = bn / NN; int n = bn & (NN-1);
  float v = 0.f;
  #pragma unroll
  for (int hh = 0; hh < NH; ++hh) v += att[((size_t)(b*NH + hh)*NN + n)*DK + d];
  v *= 0.25f;
  float s = v;
  #pragma unroll
  for (int o = 32; o >= 1; o >>= 1) s += __shfl_xor(s, o);
  float mu = s * (1.f/DK);
  float dv = v - mu;
  float q = dv*dv;
  #pragma unroll
  for (int o = 32; o >= 1; o >>= 1) q += __shfl_xor(q, o);
  float var = q * (1.f/DK);
  float ln = dv * rsqrtf(var + 1e-5f) * sc[d] + bi[d];
  out[(size_t)bn*DK + d] = ln;
}

// ---------------------------------------------------------------------------
extern "C" void kernel_launch(void* const* d_in, const int* in_sizes, int n_in,
                              void* d_out, int out_size, void* d_ws, size_t ws_size,
                              hipStream_t stream){
  const float* nf   = (const float*)d_in[0];
  const int*   adj  = (const int*)d_in[1];
  const float* Wp   = (const float*)d_in[2];
  const float* bp   = (const float*)d_in[3];
  const float* W1   = (const float*)d_in[4];
  const float* a1   = (const float*)d_in[5];
  const float* ln1s = (const float*)d_in[6];
  const float* ln1b = (const float*)d_in[7];
  const float* W2   = (const float*)d_in[8];
  const float* a2   = (const float*)d_in[9];
  const float* ln2s = (const float*)d_in[10];
  const float* ln2b = (const float*)d_in[11];

  float* ws   = (float*)d_ws;
  float* x    = ws;                  // 2,097,152 f32
  float* h    = ws +   2097152;      // 2,097,152 f32
  float* att  = ws + 2*2097152;      // 2,097,152 f32
  float* srcb = ws + 3*2097152;      // 32,768
  float* dstb = srcb + 32768;        // 32,768
  float* Mx   = dstb + 32768;        // 16 (+pad)
  _Float16* hT = (_Float16*)(ws + 3*2097152 + 65536 + 64);  // 2,097,152 f16 = 4 MB

  k_proj <<<BB*NN,       256, 0, stream>>>(nf, Wp, bp, x);
  k_head <<<BB*NH*NN/4,  256, 0, stream>>>(x, W1, a1, h, srcb, dstb);
  k_dmax <<<BB*NH,       256, 0, stream>>>(dstb, Mx);
  k_tr   <<<BB*NH*32,    256, 0, stream>>>(h, hT);
  k_attn3<<<BB*NH*NN/128,256, 0, stream>>>(srcb, dstb, Mx, hT, adj, att);
  k_ln1  <<<BB*NN,       256, 0, stream>>>(att, ln1s, ln1b, x);
  k_head <<<BB*NH*NN/4,  256, 0, stream>>>(x, W2, a2, h, srcb, dstb);
  k_dmax <<<BB*NH,       256, 0, stream>>>(dstb, Mx);
  k_tr   <<<BB*NH*32,    256, 0, stream>>>(h, hT);
  k_attn3<<<BB*NH*NN/128,256, 0, stream>>>(srcb, dstb, Mx, hT, adj, att);
  k_final<<<BB*NN/4,     256, 0, stream>>>(att, ln2s, ln2b, (float*)d_out);
}

// Round 5
// 259.673 us; speedup vs baseline: 5.1483x; 1.3178x over previous
//
#include <hip/hip_runtime.h>
#include <hip/hip_bf16.h>
#include <hip/hip_fp16.h>

// Shapes (fixed by the reference)
#define BB   4
#define NN   2048
#define FIN  128
#define HD   256
#define NH   4
#define DK   64
#define NEGV (-1000000000.0f)
#define RT   64      // rows per attention block

typedef _Float16 f16x8 __attribute__((ext_vector_type(8)));
typedef float    f32x16 __attribute__((ext_vector_type(16)));

// XOR swizzle: flip byte bits 4-6 with row bits (row = byte>>7, 128B rows)
__device__ __forceinline__ int SWZ(int b){ return b ^ (((b >> 7) & 7) << 4); }

// ---------------------------------------------------------------------------
// K1: x[b,n,c] = sum_i nf[b,n,i]*Wp[i,c] + bp[c]
__global__ void __launch_bounds__(256) k_proj(const float* __restrict__ nf,
                                              const float* __restrict__ Wp,
                                              const float* __restrict__ bp,
                                              float* __restrict__ x){
  int bn = blockIdx.x; int c = threadIdx.x;
  __shared__ float xs[FIN];
  if (c < FIN) xs[c] = nf[bn*FIN + c];
  __syncthreads();
  float acc = bp[c];
  #pragma unroll 8
  for (int i = 0; i < FIN; ++i) acc = fmaf(xs[i], Wp[i*HD + c], acc);
  x[bn*HD + c] = acc;
}

// ---------------------------------------------------------------------------
// K1b: bitmask pack. Wave w packs row blockIdx.x*4+w: mask[row][mt] = ballot(adj!=0)
__global__ void __launch_bounds__(256) k_mask(const int* __restrict__ adj,
                                              unsigned long long* __restrict__ mask){
  int w = threadIdx.x >> 6, lane = threadIdx.x & 63;
  int row = blockIdx.x*4 + w;                 // row in [0, BB*NN)
  const int* ar = adj + (size_t)row*NN;
  unsigned long long* mr = mask + (size_t)row*32;
  #pragma unroll 4
  for (int mt = 0; mt < 32; ++mt){
    int av = ar[mt*64 + lane];
    unsigned long long bal = __ballot(av != 0);
    if (lane == 0) mr[mt] = bal;
  }
}

// ---------------------------------------------------------------------------
// K2: h[b,hh,n,d] = sum_i x[b,n,i]*W[hh,i,d]; src/dst = dot(h, a_src/a_dst)
// 8 rows per block, 2 rows per thread (shared W loads)
__global__ void __launch_bounds__(256) k_head(const float* __restrict__ x,
                                              const float* __restrict__ W,
                                              const float* __restrict__ a,
                                              float* __restrict__ h,
                                              float* __restrict__ src,
                                              float* __restrict__ dst){
  int tile = blockIdx.x;
  int nt = tile & (NN/8 - 1);
  int bh = tile / (NN/8);
  int b  = bh >> 2; int hh = bh & 3;
  int w = threadIdx.x >> 6; int d = threadIdx.x & 63;
  __shared__ float xs[8][HD];
  for (int k = threadIdx.x; k < 8*HD; k += 256){
    int r = k >> 8; int cc = k & 255;
    xs[r][cc] = x[(b*NN + nt*8 + r)*HD + cc];
  }
  __syncthreads();
  const float* Wh = W + hh*HD*DK;
  float a0 = 0.f, a1 = 0.f;
  #pragma unroll 8
  for (int i = 0; i < HD; ++i){
    float wv = Wh[i*DK + d];
    a0 = fmaf(xs[w][i],   wv, a0);
    a1 = fmaf(xs[w+4][i], wv, a1);
  }
  int n0 = nt*8 + w, n1 = n0 + 4;
  h[(size_t)(bh*NN + n0)*DK + d] = a0;
  h[(size_t)(bh*NN + n1)*DK + d] = a1;
  float avs = a[hh*2*DK + d], avd = a[hh*2*DK + DK + d];
  float s0 = a0*avs, t0 = a0*avd, s1 = a1*avs, t1 = a1*avd;
  #pragma unroll
  for (int o = 32; o >= 1; o >>= 1){
    s0 += __shfl_xor(s0, o); t0 += __shfl_xor(t0, o);
    s1 += __shfl_xor(s1, o); t1 += __shfl_xor(t1, o);
  }
  if (d == 0){
    src[bh*NN + n0] = s0; dst[bh*NN + n0] = t0;
    src[bh*NN + n1] = s1; dst[bh*NN + n1] = t1;
  }
}

// ---------------------------------------------------------------------------
// K2b: Mx[bh] = max_m dst[bh, m]
__global__ void __launch_bounds__(256) k_dmax(const float* __restrict__ dst,
                                              float* __restrict__ Mx){
  int bh = blockIdx.x; int t = threadIdx.x;
  float m = -INFINITY;
  for (int i = t; i < NN; i += 256) m = fmaxf(m, dst[bh*NN + i]);
  __shared__ float red[256];
  red[t] = m; __syncthreads();
  for (int o = 128; o >= 1; o >>= 1){ if (t < o) red[t] = fmaxf(red[t], red[t+o]); __syncthreads(); }
  if (t == 0) Mx[bh] = red[0];
}

// ---------------------------------------------------------------------------
// K2c: transpose+convert+PERMUTE: hT[bh][mt][d][slot] (f16), slot 2j -> m0+j,
// slot 2j+1 -> m0+32+j  (matches ballot bit layout & P-pair writes)
__global__ void __launch_bounds__(256) k_tr(const float* __restrict__ h,
                                            _Float16* __restrict__ hT){
  int mt = blockIdx.x & 31;
  int bh = blockIdx.x >> 5;
  int m0 = mt * 64;
  int t = threadIdx.x;
  __shared__ __align__(16) _Float16 lt[64][72];   // [d][m local]
  #pragma unroll
  for (int k = 0; k < 4; ++k){
    int idx = k*256 + t;
    int m = idx >> 4;             // 0..63
    int d0 = (idx & 15) * 4;      // 0..60
    float4 v = *(const float4*)&h[(size_t)(bh*NN + m0 + m)*DK + d0];
    lt[d0+0][m] = (_Float16)v.x;
    lt[d0+1][m] = (_Float16)v.y;
    lt[d0+2][m] = (_Float16)v.z;
    lt[d0+3][m] = (_Float16)v.w;
  }
  __syncthreads();
  int d = t >> 2, seg = t & 3;
  f16x8 lo = *(const f16x8*)&lt[d][seg*8];
  f16x8 hi = *(const f16x8*)&lt[d][32 + seg*8];
  f16x8 o0, o1;
  o0[0]=lo[0]; o0[1]=hi[0]; o0[2]=lo[1]; o0[3]=hi[1];
  o0[4]=lo[2]; o0[5]=hi[2]; o0[6]=lo[3]; o0[7]=hi[3];
  o1[0]=lo[4]; o1[1]=hi[4]; o1[2]=lo[5]; o1[3]=hi[5];
  o1[4]=lo[6]; o1[5]=hi[6]; o1[6]=lo[7]; o1[7]=hi[7];
  _Float16* dstp = hT + (size_t)bh*DK*NN + mt*4096 + d*64 + seg*16;
  *(f16x8*)dstp = o0;
  *(f16x8*)(dstp + 8) = o1;
}

// ---------------------------------------------------------------------------
// K3: MFMA attention. Block = 64 rows of one (b,hh); 4 waves (2x2); BK=64.
// Bitmask adjacency; bound-max softmax; lane l5 scores m-pair (m0+l5, m0+32+l5).
__global__ void __launch_bounds__(256) k_attn4(const float* __restrict__ src,
                                               const float* __restrict__ dst,
                                               const float* __restrict__ Mx,
                                               const _Float16* __restrict__ hT,
                                               const unsigned long long* __restrict__ mask,
                                               float* __restrict__ out){
  int rb = blockIdx.x & 31;
  int bh = blockIdx.x >> 5;
  int b  = bh >> 2;
  int n0 = rb * RT;
  int t = threadIdx.x;
  int w = t >> 6, l = t & 63;
  int lh = l >> 5, l5 = l & 31;
  int wr = (w >> 1) & 1, wc = w & 1;

  __shared__ __align__(16) char ps[2][64*128];   // P tile f16: [row][64 slots]
  __shared__ __align__(16) char hs[2][64*128];   // hT tile f16: [d][64 slots]
  __shared__ float rs[RT];

  float Mbh = Mx[bh];
  float srcv[8], bnd[8], psum[8];
  const unsigned long long* mrow = mask + ((size_t)(b*NN) + n0 + w*2 + lh)*32;
  #pragma unroll
  for (int q = 0; q < 8; ++q){
    int r = q*8 + w*2 + lh;
    float s = src[bh*NN + n0 + r];
    srcv[q] = s;
    float bv = s + Mbh;
    bnd[q] = (bv >= 0.f) ? bv : 0.2f*bv;
    psum[q] = 0.f;
  }
  f32x16 acc = {};

  const _Float16* hTb = hT + (size_t)bh*DK*NN;
  int sd = t >> 2, sseg = t & 3;                 // staging role

  for (int mt = 0; mt < 32; ++mt){
    int cur = mt & 1;
    int m0 = mt * 64;

    // ---- stage hT tile (coalesced global -> swizzled LDS)
    const _Float16* gsrc = hTb + mt*4096 + sd*64 + sseg*16;
    f16x8 hv0 = *(const f16x8*)gsrc;
    f16x8 hv1 = *(const f16x8*)(gsrc + 8);
    int hb0 = sd*128 + sseg*32;
    *(f16x8*)&hs[cur][SWZ(hb0)]      = hv0;
    *(f16x8*)&hs[cur][SWZ(hb0 + 16)] = hv1;

    // ---- batched mask loads (broadcast u64 per 32 lanes)
    unsigned long long msk[8];
    #pragma unroll
    for (int q = 0; q < 8; ++q) msk[q] = mrow[(size_t)q*8*32 + mt];

    float dm0 = dst[bh*NN + m0 + l5];
    float dm1 = dst[bh*NN + m0 + 32 + l5];

    // ---- score phase: row r = q*8+w*2+lh, m pair (m0+l5, m0+32+l5)
    #pragma unroll
    for (int q = 0; q < 8; ++q){
      int r = q*8 + w*2 + lh;
      unsigned lo = (unsigned)msk[q];
      unsigned hi = (unsigned)(msk[q] >> 32);
      float e0 = srcv[q] + dm0;
      float e1 = srcv[q] + dm1;
      e0 = fmaxf(e0, 0.2f*e0);                   // leaky_relu
      e1 = fmaxf(e1, 0.2f*e1);
      e0 = ((lo >> l5) & 1u) ? e0 : NEGV;
      e1 = ((hi >> l5) & 1u) ? e1 : NEGV;
      float p0 = __expf(e0 - bnd[q]);
      float p1 = __expf(e1 - bnd[q]);
      psum[q] += p0 + p1;
      __half2 hp = __floats2half2_rn(p0, p1);
      *(__half2*)&ps[cur][SWZ(r*128 + l5*4)] = hp;
    }
    __syncthreads();

    // ---- MFMA phase: 4 k-steps
    #pragma unroll
    for (int kk = 0; kk < 4; ++kk){
      int co = kk*32 + lh*16;
      f16x8 A  = *(const f16x8*)&ps[cur][SWZ((wr*32 + l5)*128 + co)];
      f16x8 Bv = *(const f16x8*)&hs[cur][SWZ((wc*32 + l5)*128 + co)];
      acc = __builtin_amdgcn_mfma_f32_32x32x16_f16(A, Bv, acc, 0, 0, 0);
    }
  }

  // ---- row sums -> LDS (reduce over l5 within each 32-lane half)
  #pragma unroll
  for (int q = 0; q < 8; ++q){
    float s = psum[q];
    #pragma unroll
    for (int o = 16; o >= 1; o >>= 1) s += __shfl_xor(s, o);
    if (l5 == 0) rs[q*8 + w*2 + lh] = s;
  }
  __syncthreads();

  // ---- normalize + store (C layout: col=lane&31, row=(g&3)+8*(g>>2)+4*lh)
  #pragma unroll
  for (int g = 0; g < 16; ++g){
    int rbase = (g & 3) + 8*(g >> 2) + 4*lh;
    int col = wc*32 + l5;
    int row = wr*32 + rbase;
    out[((size_t)bh*NN + n0 + row)*DK + col] = acc[g] / rs[row];
  }
}

// ---------------------------------------------------------------------------
// K4: x[b,j,:] += elu(LN(x1[b,j,:])), x1 = reshape-reinterpret of att1
__global__ void __launch_bounds__(256) k_ln1(const float* __restrict__ att,
                                             const float* __restrict__ sc,
                                             const float* __restrict__ bi,
                                             float* __restrict__ x){
  int j = blockIdx.x & (NN-1);
  int b = blockIdx.x / NN;
  int c = threadIdx.x;
  int hh = j >> 9;
  int node = ((j & 511) << 2) + (c >> 6);
  int d = c & 63;
  float v = att[(((size_t)(b*NH + hh)*NN) + node)*DK + d];
  __shared__ float red[256];
  red[c] = v; __syncthreads();
  for (int o = 128; o >= 1; o >>= 1){ if (c < o) red[c] += red[c+o]; __syncthreads(); }
  float mu = red[0] * (1.f/HD); __syncthreads();
  float dv = v - mu;
  red[c] = dv*dv; __syncthreads();
  for (int o = 128; o >= 1; o >>= 1){ if (c < o) red[c] += red[c+o]; __syncthreads(); }
  float var = red[0] * (1.f/HD);
  float ln = dv * rsqrtf(var + 1e-5f) * sc[c] + bi[c];
  float el = (ln > 0.f) ? ln : (__expf(ln) - 1.f);
  x[(size_t)blockIdx.x*HD + c] += el;
}

// ---------------------------------------------------------------------------
// K5: out[b,n,d] = LN_64( mean_h att2[b,h,n,d] )
__global__ void __launch_bounds__(256) k_final(const float* __restrict__ att,
                                               const float* __restrict__ sc,
                                               const float* __restrict__ bi,
                                               float* __restrict__ out){
  int w = threadIdx.x >> 6; int d = threadIdx.x & 63;
  int bn = blockIdx.x*4 + w;
  int b = bn / NN; int n = bn & (NN-1);
  float v = 0.f;
  #pragma unroll
  for (int hh = 0; hh < NH; ++hh) v += att[((size_t)(b*NH + hh)*NN + n)*DK + d];
  v *= 0.25f;
  float s = v;
  #pragma unroll
  for (int o = 32; o >= 1; o >>= 1) s += __shfl_xor(s, o);
  float mu = s * (1.f/DK);
  float dv = v - mu;
  float q = dv*dv;
  #pragma unroll
  for (int o = 32; o >= 1; o >>= 1) q += __shfl_xor(q, o);
  float var = q * (1.f/DK);
  float ln = dv * rsqrtf(var + 1e-5f) * sc[d] + bi[d];
  out[(size_t)bn*DK + d] = ln;
}

// ---------------------------------------------------------------------------
extern "C" void kernel_launch(void* const* d_in, const int* in_sizes, int n_in,
                              void* d_out, int out_size, void* d_ws, size_t ws_size,
                              hipStream_t stream){
  const float* nf   = (const float*)d_in[0];
  const int*   adj  = (const int*)d_in[1];
  const float* Wp   = (const float*)d_in[2];
  const float* bp   = (const float*)d_in[3];
  const float* W1   = (const float*)d_in[4];
  const float* a1   = (const float*)d_in[5];
  const float* ln1s = (const float*)d_in[6];
  const float* ln1b = (const float*)d_in[7];
  const float* W2   = (const float*)d_in[8];
  const float* a2   = (const float*)d_in[9];
  const float* ln2s = (const float*)d_in[10];
  const float* ln2b = (const float*)d_in[11];

  float* ws   = (float*)d_ws;
  float* x    = ws;                  // 2,097,152 f32
  float* h    = ws +   2097152;      // 2,097,152 f32
  float* att  = ws + 2*2097152;      // 2,097,152 f32
  float* srcb = ws + 3*2097152;      // 32,768
  float* dstb = srcb + 32768;        // 32,768
  float* Mx   = dstb + 32768;        // 64 (pad)
  _Float16* hT = (_Float16*)(Mx + 64);               // 2,097,152 f16 = 4 MB
  unsigned long long* mask = (unsigned long long*)(hT + 2097152);  // 2 MB

  k_proj <<<BB*NN,        256, 0, stream>>>(nf, Wp, bp, x);
  k_mask <<<BB*NN/4,      256, 0, stream>>>(adj, mask);
  k_head <<<BB*NH*NN/8,   256, 0, stream>>>(x, W1, a1, h, srcb, dstb);
  k_dmax <<<BB*NH,        256, 0, stream>>>(dstb, Mx);
  k_tr   <<<BB*NH*32,     256, 0, stream>>>(h, hT);
  k_attn4<<<BB*NH*NN/RT,  256, 0, stream>>>(srcb, dstb, Mx, hT, mask, att);
  k_ln1  <<<BB*NN,        256, 0, stream>>>(att, ln1s, ln1b, x);
  k_head <<<BB*NH*NN/8,   256, 0, stream>>>(x, W2, a2, h, srcb, dstb);
  k_dmax <<<BB*NH,        256, 0, stream>>>(dstb, Mx);
  k_tr   <<<BB*NH*32,     256, 0, stream>>>(h, hT);
  k_attn4<<<BB*NH*NN/RT,  256, 0, stream>>>(srcb, dstb, Mx, hT, mask, att);
  k_final<<<BB*NN/4,      256, 0, stream>>>(att, ln2s, ln2b, (float*)d_out);
}

// Round 6
// 209.180 us; speedup vs baseline: 6.3911x; 1.2414x over previous
//
#include <hip/hip_runtime.h>
#include <hip/hip_bf16.h>
#include <hip/hip_fp16.h>

// Shapes (fixed by the reference)
#define BB   4
#define NN   2048
#define FIN  128
#define HD   256
#define NH   4
#define DK   64
#define NEGV (-1000000000.0f)
#define RT   32      // rows per attention block
#define LOG2E 1.4426950408889634f

typedef _Float16 f16x8 __attribute__((ext_vector_type(8)));
typedef float    f32x16 __attribute__((ext_vector_type(16)));
typedef unsigned long long u64;

// XOR swizzle: flip byte bits 4-6 with row bits (row = byte>>7, 128B rows)
__device__ __forceinline__ int SWZ(int b){ return b ^ (((b >> 7) & 7) << 4); }

__device__ __forceinline__ float fexp2(float x){
#if __has_builtin(__builtin_amdgcn_exp2f)
  return __builtin_amdgcn_exp2f(x);
#else
  return __exp2f(x);
#endif
}

// ---------------------------------------------------------------------------
// K1: x[b,n,c] = sum_i nf[b,n,i]*Wp[i,c] + bp[c]. 16 rows/block, 512 blocks.
__global__ void __launch_bounds__(256) k_proj(const float* __restrict__ nf,
                                              const float* __restrict__ Wp,
                                              const float* __restrict__ bp,
                                              float* __restrict__ x){
  int r0 = blockIdx.x * 16;
  int c = threadIdx.x;
  __shared__ __align__(16) float xs[16][FIN];
  for (int k = threadIdx.x; k < 16*FIN/4; k += 256){
    int r = k >> 5; int cc = (k & 31) * 4;
    *(float4*)&xs[r][cc] = *(const float4*)&nf[(size_t)(r0 + r)*FIN + cc];
  }
  __syncthreads();
  float acc[16];
  float bv = bp[c];
  #pragma unroll
  for (int r = 0; r < 16; ++r) acc[r] = bv;
  #pragma unroll 4
  for (int i = 0; i < FIN; i += 4){
    float w0 = Wp[(i+0)*HD + c];
    float w1 = Wp[(i+1)*HD + c];
    float w2 = Wp[(i+2)*HD + c];
    float w3 = Wp[(i+3)*HD + c];
    #pragma unroll
    for (int r = 0; r < 16; ++r){
      float4 xv = *(const float4*)&xs[r][i];
      acc[r] = fmaf(xv.x, w0, acc[r]);
      acc[r] = fmaf(xv.y, w1, acc[r]);
      acc[r] = fmaf(xv.z, w2, acc[r]);
      acc[r] = fmaf(xv.w, w3, acc[r]);
    }
  }
  #pragma unroll
  for (int r = 0; r < 16; ++r) x[(size_t)(r0 + r)*HD + c] = acc[r];
}

// ---------------------------------------------------------------------------
// K1b: bitmask pack. Wave w packs row blockIdx.x*4+w: mask[row][mt] = ballot(adj!=0)
__global__ void __launch_bounds__(256) k_mask(const int* __restrict__ adj,
                                              u64* __restrict__ mask){
  int w = threadIdx.x >> 6, lane = threadIdx.x & 63;
  int row = blockIdx.x*4 + w;
  const int* ar = adj + (size_t)row*NN;
  u64* mr = mask + (size_t)row*32;
  #pragma unroll 4
  for (int mt = 0; mt < 32; ++mt){
    int av = ar[mt*64 + lane];
    u64 bal = __ballot(av != 0);
    if (lane == 0) mr[mt] = bal;
  }
}

// ---------------------------------------------------------------------------
// K2: h = x@W[hh]; src/dst = (h . a_src/a_dst) * LOG2E (pre-scaled for exp2).
// 16 rows/block, 4 rows/thread.
__global__ void __launch_bounds__(256) k_head(const float* __restrict__ x,
                                              const float* __restrict__ W,
                                              const float* __restrict__ a,
                                              float* __restrict__ h,
                                              float* __restrict__ src,
                                              float* __restrict__ dst){
  int tile = blockIdx.x;
  int nt = tile & (NN/16 - 1);
  int bh = tile / (NN/16);
  int b  = bh >> 2; int hh = bh & 3;
  int w = threadIdx.x >> 6; int d = threadIdx.x & 63;
  __shared__ __align__(16) float xs[16][HD];
  for (int k = threadIdx.x; k < 16*HD/4; k += 256){
    int r = k >> 6; int cc = (k & 63) * 4;
    *(float4*)&xs[r][cc] = *(const float4*)&x[(size_t)(b*NN + nt*16 + r)*HD + cc];
  }
  __syncthreads();
  const float* Wh = W + hh*HD*DK;
  float a0 = 0.f, a1 = 0.f, a2 = 0.f, a3 = 0.f;
  #pragma unroll 4
  for (int i = 0; i < HD; i += 4){
    float w0 = Wh[(i+0)*DK + d];
    float w1 = Wh[(i+1)*DK + d];
    float w2 = Wh[(i+2)*DK + d];
    float w3 = Wh[(i+3)*DK + d];
    float4 x0 = *(const float4*)&xs[w   ][i];
    float4 x1 = *(const float4*)&xs[w+ 4][i];
    float4 x2 = *(const float4*)&xs[w+ 8][i];
    float4 x3 = *(const float4*)&xs[w+12][i];
    a0 = fmaf(x0.x,w0,a0); a0 = fmaf(x0.y,w1,a0); a0 = fmaf(x0.z,w2,a0); a0 = fmaf(x0.w,w3,a0);
    a1 = fmaf(x1.x,w0,a1); a1 = fmaf(x1.y,w1,a1); a1 = fmaf(x1.z,w2,a1); a1 = fmaf(x1.w,w3,a1);
    a2 = fmaf(x2.x,w0,a2); a2 = fmaf(x2.y,w1,a2); a2 = fmaf(x2.z,w2,a2); a2 = fmaf(x2.w,w3,a2);
    a3 = fmaf(x3.x,w0,a3); a3 = fmaf(x3.y,w1,a3); a3 = fmaf(x3.z,w2,a3); a3 = fmaf(x3.w,w3,a3);
  }
  int nb = nt*16;
  h[(size_t)(bh*NN + nb + w   )*DK + d] = a0;
  h[(size_t)(bh*NN + nb + w+ 4)*DK + d] = a1;
  h[(size_t)(bh*NN + nb + w+ 8)*DK + d] = a2;
  h[(size_t)(bh*NN + nb + w+12)*DK + d] = a3;
  float avs = a[hh*2*DK + d] * LOG2E;
  float avd = a[hh*2*DK + DK + d] * LOG2E;
  float s0 = a0*avs, t0 = a0*avd, s1 = a1*avs, t1 = a1*avd;
  float s2 = a2*avs, t2 = a2*avd, s3 = a3*avs, t3 = a3*avd;
  #pragma unroll
  for (int o = 32; o >= 1; o >>= 1){
    s0 += __shfl_xor(s0, o); t0 += __shfl_xor(t0, o);
    s1 += __shfl_xor(s1, o); t1 += __shfl_xor(t1, o);
    s2 += __shfl_xor(s2, o); t2 += __shfl_xor(t2, o);
    s3 += __shfl_xor(s3, o); t3 += __shfl_xor(t3, o);
  }
  if (d == 0){
    src[bh*NN + nb + w   ] = s0; dst[bh*NN + nb + w   ] = t0;
    src[bh*NN + nb + w+ 4] = s1; dst[bh*NN + nb + w+ 4] = t1;
    src[bh*NN + nb + w+ 8] = s2; dst[bh*NN + nb + w+ 8] = t2;
    src[bh*NN + nb + w+12] = s3; dst[bh*NN + nb + w+12] = t3;
  }
}

// ---------------------------------------------------------------------------
// K2b: Mx[bh] = max_m dst[bh, m]
__global__ void __launch_bounds__(256) k_dmax(const float* __restrict__ dst,
                                              float* __restrict__ Mx){
  int bh = blockIdx.x; int t = threadIdx.x;
  float m = -INFINITY;
  for (int i = t; i < NN; i += 256) m = fmaxf(m, dst[bh*NN + i]);
  __shared__ float red[256];
  red[t] = m; __syncthreads();
  for (int o = 128; o >= 1; o >>= 1){ if (t < o) red[t] = fmaxf(red[t], red[t+o]); __syncthreads(); }
  if (t == 0) Mx[bh] = red[0];
}

// ---------------------------------------------------------------------------
// K2c: transpose+convert+PERMUTE: hT[bh][mt][d][slot] (f16), slot 2j -> m0+j,
// slot 2j+1 -> m0+32+j  (matches ballot bit layout & P-pair writes)
__global__ void __launch_bounds__(256) k_tr(const float* __restrict__ h,
                                            _Float16* __restrict__ hT){
  int mt = blockIdx.x & 31;
  int bh = blockIdx.x >> 5;
  int m0 = mt * 64;
  int t = threadIdx.x;
  __shared__ __align__(16) _Float16 lt[64][72];   // [d][m local]
  #pragma unroll
  for (int k = 0; k < 4; ++k){
    int idx = k*256 + t;
    int m = idx >> 4;             // 0..63
    int d0 = (idx & 15) * 4;      // 0..60
    float4 v = *(const float4*)&h[(size_t)(bh*NN + m0 + m)*DK + d0];
    lt[d0+0][m] = (_Float16)v.x;
    lt[d0+1][m] = (_Float16)v.y;
    lt[d0+2][m] = (_Float16)v.z;
    lt[d0+3][m] = (_Float16)v.w;
  }
  __syncthreads();
  int d = t >> 2, seg = t & 3;
  f16x8 lo = *(const f16x8*)&lt[d][seg*8];
  f16x8 hi = *(const f16x8*)&lt[d][32 + seg*8];
  f16x8 o0, o1;
  o0[0]=lo[0]; o0[1]=hi[0]; o0[2]=lo[1]; o0[3]=hi[1];
  o0[4]=lo[2]; o0[5]=hi[2]; o0[6]=lo[3]; o0[7]=hi[3];
  o1[0]=lo[4]; o1[1]=hi[4]; o1[2]=lo[5]; o1[3]=hi[5];
  o1[4]=lo[6]; o1[5]=hi[6]; o1[6]=lo[7]; o1[7]=hi[7];
  _Float16* dstp = hT + (size_t)bh*DK*NN + mt*4096 + d*64 + seg*16;
  *(f16x8*)dstp = o0;
  *(f16x8*)(dstp + 8) = o1;
}

// ---------------------------------------------------------------------------
// K3: MFMA attention. Block = 32 rows of one (b,hh); 4 waves; wave = (wr,wc):
// wr = k-chunk half, wc = col half. BK=64 per iter; partial accs combined via LDS.
// Bitmask adjacency; bound-max softmax in exp2 domain (src/dst pre-scaled).
__global__ void __launch_bounds__(256, 4) k_attn5(const float* __restrict__ src,
                                                  const float* __restrict__ dst,
                                                  const float* __restrict__ Mx,
                                                  const _Float16* __restrict__ hT,
                                                  const u64* __restrict__ mask,
                                                  float* __restrict__ out){
  int rb = blockIdx.x & 63;
  int bh = blockIdx.x >> 6;
  int b  = bh >> 2;
  int n0 = rb * RT;
  int t = threadIdx.x;
  int w = t >> 6, l = t & 63;
  int lh = l >> 5, l5 = l & 31;
  int wr = w >> 1, wc = w & 1;

  __shared__ __align__(16) char ps[2][32*128];   // P tile f16: [row][64 slots], 8KB
  __shared__ __align__(16) char hs[2][64*128];   // hT tile f16: [d][64 slots], 16KB
  __shared__ float rs[RT];

  float Mbh = Mx[bh];
  float srcv[4], bnd[4], psum[4];
  const u64* mrow = mask + ((size_t)(b*NN) + n0 + w*8 + lh*4)*32;
  #pragma unroll
  for (int q = 0; q < 4; ++q){
    int r = w*8 + lh*4 + q;
    float s = src[bh*NN + n0 + r];
    srcv[q] = s;
    float bv = s + Mbh;
    bnd[q] = fmaxf(bv, 0.2f*bv);
    psum[q] = 0.f;
  }
  f32x16 acc = {};

  const _Float16* gptr = hT + (size_t)bh*DK*NN + (t>>2)*64 + (t&3)*16;
  const float* dstp = dst + bh*NN;
  int hb0 = (t>>2)*128 + (t&3)*32;
  int swzh0 = SWZ(hb0), swzh1 = SWZ(hb0 + 16);

  for (int mt = 0; mt < 32; ++mt){
    int cur = mt & 1;

    // ---- stage hT tile (coalesced global -> swizzled LDS)
    f16x8 hv0 = *(const f16x8*)gptr;
    f16x8 hv1 = *(const f16x8*)(gptr + 8);
    gptr += 4096;
    *(f16x8*)&hs[cur][swzh0] = hv0;
    *(f16x8*)&hs[cur][swzh1] = hv1;

    // ---- masks (imm-offset batch) + dst pair
    u64 mk0 = mrow[mt], mk1 = mrow[32 + mt], mk2 = mrow[64 + mt], mk3 = mrow[96 + mt];
    float dm0 = dstp[l5];
    float dm1 = dstp[32 + l5];
    dstp += 64;

    // ---- score phase: row r = w*8+lh*4+q, m pair (m0+l5, m0+32+l5)
    u64 mks[4] = {mk0, mk1, mk2, mk3};
    #pragma unroll
    for (int q = 0; q < 4; ++q){
      int r = w*8 + lh*4 + q;
      unsigned lo = (unsigned)mks[q];
      unsigned hi = (unsigned)(mks[q] >> 32);
      float e0 = srcv[q] + dm0;
      float e1 = srcv[q] + dm1;
      e0 = fmaxf(e0, 0.2f*e0);                   // leaky_relu (scaled domain)
      e1 = fmaxf(e1, 0.2f*e1);
      e0 = ((lo >> l5) & 1u) ? e0 : NEGV;
      e1 = ((hi >> l5) & 1u) ? e1 : NEGV;
      float p0 = fexp2(e0 - bnd[q]);
      float p1 = fexp2(e1 - bnd[q]);
      psum[q] += p0 + p1;
      __half2 hp = __floats2half2_rn(p0, p1);
      *(__half2*)&ps[cur][SWZ(r*128 + l5*4)] = hp;
    }
    __syncthreads();

    // ---- MFMA phase: this wave's k-chunk (2 of 4 k-steps)
    #pragma unroll
    for (int kk = 0; kk < 2; ++kk){
      int co = (wr*2 + kk)*32 + lh*16;
      f16x8 A  = *(const f16x8*)&ps[cur][SWZ(l5*128 + co)];
      f16x8 Bv = *(const f16x8*)&hs[cur][SWZ((wc*32 + l5)*128 + co)];
      acc = __builtin_amdgcn_mfma_f32_32x32x16_f16(A, Bv, acc, 0, 0, 0);
    }
  }

  // ---- row sums -> LDS (reduce over l5 within each 32-lane half)
  #pragma unroll
  for (int q = 0; q < 4; ++q){
    float s = psum[q];
    #pragma unroll
    for (int o = 16; o >= 1; o >>= 1) s += __shfl_xor(s, o);
    if (l5 == 0) rs[w*8 + lh*4 + q] = s;
  }

  // ---- combine k-halves via LDS (reuse ps as 32x64 f32 = 8KB), normalize, store
  float* cs = (float*)&ps[0][0];
  if (wr == 1){
    #pragma unroll
    for (int g = 0; g < 16; ++g){
      int row = (g & 3) + 8*(g >> 2) + 4*lh;
      cs[row*64 + wc*32 + l5] = acc[g];
    }
  }
  __syncthreads();
  if (wr == 0){
    #pragma unroll
    for (int g = 0; g < 16; ++g){
      int row = (g & 3) + 8*(g >> 2) + 4*lh;
      int col = wc*32 + l5;
      float v = acc[g] + cs[row*64 + col];
      out[((size_t)bh*NN + n0 + row)*DK + col] = v / rs[row];
    }
  }
}

// ---------------------------------------------------------------------------
// K4: x[b,j,:] += elu(LN(x1[b,j,:])), x1 = reshape-reinterpret of att1
__global__ void __launch_bounds__(256) k_ln1(const float* __restrict__ att,
                                             const float* __restrict__ sc,
                                             const float* __restrict__ bi,
                                             float* __restrict__ x){
  int j = blockIdx.x & (NN-1);
  int b = blockIdx.x / NN;
  int c = threadIdx.x;
  int hh = j >> 9;
  int node = ((j & 511) << 2) + (c >> 6);
  int d = c & 63;
  float v = att[(((size_t)(b*NH + hh)*NN) + node)*DK + d];
  __shared__ float red[256];
  red[c] = v; __syncthreads();
  for (int o = 128; o >= 1; o >>= 1){ if (c < o) red[c] += red[c+o]; __syncthreads(); }
  float mu = red[0] * (1.f/HD); __syncthreads();
  float dv = v - mu;
  red[c] = dv*dv; __syncthreads();
  for (int o = 128; o >= 1; o >>= 1){ if (c < o) red[c] += red[c+o]; __syncthreads(); }
  float var = red[0] * (1.f/HD);
  float ln = dv * rsqrtf(var + 1e-5f) * sc[c] + bi[c];
  float el = (ln > 0.f) ? ln : (__expf(ln) - 1.f);
  x[(size_t)blockIdx.x*HD + c] += el;
}

// ---------------------------------------------------------------------------
// K5: out[b,n,d] = LN_64( mean_h att2[b,h,n,d] )
__global__ void __launch_bounds__(256) k_final(const float* __restrict__ att,
                                               const float* __restrict__ sc,
                                               const float* __restrict__ bi,
                                               float* __restrict__ out){
  int w = threadIdx.x >> 6; int d = threadIdx.x & 63;
  int bn = blockIdx.x*4 + w;
  int b = bn / NN; int n = bn & (NN-1);
  float v = 0.f;
  #pragma unroll
  for (int hh = 0; hh < NH; ++hh) v += att[((size_t)(b*NH + hh)*NN + n)*DK + d];
  v *= 0.25f;
  float s = v;
  #pragma unroll
  for (int o = 32; o >= 1; o >>= 1) s += __shfl_xor(s, o);
  float mu = s * (1.f/DK);
  float dv = v - mu;
  float q = dv*dv;
  #pragma unroll
  for (int o = 32; o >= 1; o >>= 1) q += __shfl_xor(q, o);
  float var = q * (1.f/DK);
  float ln = dv * rsqrtf(var + 1e-5f) * sc[d] + bi[d];
  out[(size_t)bn*DK + d] = ln;
}

// ---------------------------------------------------------------------------
extern "C" void kernel_launch(void* const* d_in, const int* in_sizes, int n_in,
                              void* d_out, int out_size, void* d_ws, size_t ws_size,
                              hipStream_t stream){
  const float* nf   = (const float*)d_in[0];
  const int*   adj  = (const int*)d_in[1];
  const float* Wp   = (const float*)d_in[2];
  const float* bp   = (const float*)d_in[3];
  const float* W1   = (const float*)d_in[4];
  const float* a1   = (const float*)d_in[5];
  const float* ln1s = (const float*)d_in[6];
  const float* ln1b = (const float*)d_in[7];
  const float* W2   = (const float*)d_in[8];
  const float* a2   = (const float*)d_in[9];
  const float* ln2s = (const float*)d_in[10];
  const float* ln2b = (const float*)d_in[11];

  float* ws   = (float*)d_ws;
  float* x    = ws;                  // 2,097,152 f32
  float* h    = ws +   2097152;      // 2,097,152 f32
  float* att  = ws + 2*2097152;      // 2,097,152 f32
  float* srcb = ws + 3*2097152;      // 32,768
  float* dstb = srcb + 32768;        // 32,768
  float* Mx   = dstb + 32768;        // 64 (pad)
  _Float16* hT = (_Float16*)(Mx + 64);               // 2,097,152 f16 = 4 MB
  u64* mask = (u64*)(hT + 2097152);                  // 2 MB

  k_proj <<<BB*NN/16,     256, 0, stream>>>(nf, Wp, bp, x);
  k_mask <<<BB*NN/4,      256, 0, stream>>>(adj, mask);
  k_head <<<BB*NH*NN/16,  256, 0, stream>>>(x, W1, a1, h, srcb, dstb);
  k_dmax <<<BB*NH,        256, 0, stream>>>(dstb, Mx);
  k_tr   <<<BB*NH*32,     256, 0, stream>>>(h, hT);
  k_attn5<<<BB*NH*NN/RT,  256, 0, stream>>>(srcb, dstb, Mx, hT, mask, att);
  k_ln1  <<<BB*NN,        256, 0, stream>>>(att, ln1s, ln1b, x);
  k_head <<<BB*NH*NN/16,  256, 0, stream>>>(x, W2, a2, h, srcb, dstb);
  k_dmax <<<BB*NH,        256, 0, stream>>>(dstb, Mx);
  k_tr   <<<BB*NH*32,     256, 0, stream>>>(h, hT);
  k_attn5<<<BB*NH*NN/RT,  256, 0, stream>>>(srcb, dstb, Mx, hT, mask, att);
  k_final<<<BB*NN/4,      256, 0, stream>>>(att, ln2s, ln2b, (float*)d_out);
}

// Round 7
// 185.432 us; speedup vs baseline: 7.2096x; 1.1281x over previous
//
#include <hip/hip_runtime.h>
#include <hip/hip_bf16.h>
#include <hip/hip_fp16.h>

// Shapes (fixed by the reference)
#define BB   4
#define NN   2048
#define FIN  128
#define HD   256
#define NH   4
#define DK   64
#define NEGV (-1000000000.0f)
#define LOG2E 1.4426950408889634f

typedef _Float16 f16x8 __attribute__((ext_vector_type(8)));
typedef _Float16 f16x4 __attribute__((ext_vector_type(4)));
typedef float    f32x16 __attribute__((ext_vector_type(16)));
typedef unsigned long long u64;

// XOR swizzle for 128B-row LDS tiles: flip byte bits 4-6 with row bits
__device__ __forceinline__ int SWZ(int b){ return b ^ (((b >> 7) & 7) << 4); }

__device__ __forceinline__ float fexp2(float x){
#if __has_builtin(__builtin_amdgcn_exp2f)
  return __builtin_amdgcn_exp2f(x);
#else
  return __exp2f(x);
#endif
}

// ---------------------------------------------------------------------------
// K1: x[b,n,c] = sum_i nf[b,n,i]*Wp[i,c] + bp[c]. 16 rows/block.
__global__ void __launch_bounds__(256) k_proj(const float* __restrict__ nf,
                                              const float* __restrict__ Wp,
                                              const float* __restrict__ bp,
                                              float* __restrict__ x){
  int r0 = blockIdx.x * 16;
  int c = threadIdx.x;
  __shared__ __align__(16) float xs[16][FIN];
  for (int k = threadIdx.x; k < 16*FIN/4; k += 256){
    int r = k >> 5; int cc = (k & 31) * 4;
    *(float4*)&xs[r][cc] = *(const float4*)&nf[(size_t)(r0 + r)*FIN + cc];
  }
  __syncthreads();
  float acc[16];
  float bv = bp[c];
  #pragma unroll
  for (int r = 0; r < 16; ++r) acc[r] = bv;
  #pragma unroll 4
  for (int i = 0; i < FIN; i += 4){
    float w0 = Wp[(i+0)*HD + c];
    float w1 = Wp[(i+1)*HD + c];
    float w2 = Wp[(i+2)*HD + c];
    float w3 = Wp[(i+3)*HD + c];
    #pragma unroll
    for (int r = 0; r < 16; ++r){
      float4 xv = *(const float4*)&xs[r][i];
      acc[r] = fmaf(xv.x, w0, acc[r]);
      acc[r] = fmaf(xv.y, w1, acc[r]);
      acc[r] = fmaf(xv.z, w2, acc[r]);
      acc[r] = fmaf(xv.w, w3, acc[r]);
    }
  }
  #pragma unroll
  for (int r = 0; r < 16; ++r) x[(size_t)(r0 + r)*HD + c] = acc[r];
}

// ---------------------------------------------------------------------------
// K1b: bitmask pack, TRANSPOSED: maskT[b][mt][n] = ballot over cols mt*64..+63
__global__ void __launch_bounds__(256) k_mask(const int* __restrict__ adj,
                                              u64* __restrict__ maskT){
  int w = threadIdx.x >> 6, lane = threadIdx.x & 63;
  int row = blockIdx.x*4 + w;             // global row in [0, BB*NN)
  int b = row >> 11, n = row & (NN-1);
  const int* ar = adj + (size_t)row*NN;
  #pragma unroll 4
  for (int mt = 0; mt < 32; ++mt){
    u64 bal = __ballot(ar[mt*64 + lane] != 0);
    if (lane == 0) maskT[(size_t)(b*32 + mt)*NN + n] = bal;
  }
}

// ---------------------------------------------------------------------------
// K2: h = x@W[hh] (written DIRECTLY as f16 hT tiles); src/dst = (h.a)*LOG2E.
// 16 rows/block, 4 rows/thread. hT[bh][mt][d][mloc], plain layout.
__global__ void __launch_bounds__(256) k_head(const float* __restrict__ x,
                                              const float* __restrict__ W,
                                              const float* __restrict__ a,
                                              _Float16* __restrict__ hT,
                                              float* __restrict__ src,
                                              float* __restrict__ dst){
  int tile = blockIdx.x;
  int nt = tile & (NN/16 - 1);
  int bh = tile / (NN/16);
  int b  = bh >> 2; int hh = bh & 3;
  int w = threadIdx.x >> 6; int d = threadIdx.x & 63;
  __shared__ __align__(16) float xs[16][HD];
  __shared__ __align__(16) _Float16 ls[64][20];   // [d][row local], padded pitch
  for (int k = threadIdx.x; k < 16*HD/4; k += 256){
    int r = k >> 6; int cc = (k & 63) * 4;
    *(float4*)&xs[r][cc] = *(const float4*)&x[(size_t)(b*NN + nt*16 + r)*HD + cc];
  }
  __syncthreads();
  const float* Wh = W + hh*HD*DK;
  float a0 = 0.f, a1 = 0.f, a2 = 0.f, a3 = 0.f;
  #pragma unroll 4
  for (int i = 0; i < HD; i += 4){
    float w0 = Wh[(i+0)*DK + d];
    float w1 = Wh[(i+1)*DK + d];
    float w2 = Wh[(i+2)*DK + d];
    float w3 = Wh[(i+3)*DK + d];
    float4 x0 = *(const float4*)&xs[w   ][i];
    float4 x1 = *(const float4*)&xs[w+ 4][i];
    float4 x2 = *(const float4*)&xs[w+ 8][i];
    float4 x3 = *(const float4*)&xs[w+12][i];
    a0 = fmaf(x0.x,w0,a0); a0 = fmaf(x0.y,w1,a0); a0 = fmaf(x0.z,w2,a0); a0 = fmaf(x0.w,w3,a0);
    a1 = fmaf(x1.x,w0,a1); a1 = fmaf(x1.y,w1,a1); a1 = fmaf(x1.z,w2,a1); a1 = fmaf(x1.w,w3,a1);
    a2 = fmaf(x2.x,w0,a2); a2 = fmaf(x2.y,w1,a2); a2 = fmaf(x2.z,w2,a2); a2 = fmaf(x2.w,w3,a2);
    a3 = fmaf(x3.x,w0,a3); a3 = fmaf(x3.y,w1,a3); a3 = fmaf(x3.z,w2,a3); a3 = fmaf(x3.w,w3,a3);
  }
  // bounce h tile to LDS as f16 (transposed: [d][row])
  ls[d][w]    = (_Float16)a0;
  ls[d][w+4]  = (_Float16)a1;
  ls[d][w+8]  = (_Float16)a2;
  ls[d][w+12] = (_Float16)a3;
  // src/dst projections (pre-scaled by LOG2E for exp2 softmax)
  float avs = a[hh*2*DK + d] * LOG2E;
  float avd = a[hh*2*DK + DK + d] * LOG2E;
  float s0 = a0*avs, t0 = a0*avd, s1 = a1*avs, t1 = a1*avd;
  float s2 = a2*avs, t2 = a2*avd, s3 = a3*avs, t3 = a3*avd;
  #pragma unroll
  for (int o = 32; o >= 1; o >>= 1){
    s0 += __shfl_xor(s0, o); t0 += __shfl_xor(t0, o);
    s1 += __shfl_xor(s1, o); t1 += __shfl_xor(t1, o);
    s2 += __shfl_xor(s2, o); t2 += __shfl_xor(t2, o);
    s3 += __shfl_xor(s3, o); t3 += __shfl_xor(t3, o);
  }
  int nb = nt*16;
  if (d == 0){
    src[bh*NN + nb + w   ] = s0; dst[bh*NN + nb + w   ] = t0;
    src[bh*NN + nb + w+ 4] = s1; dst[bh*NN + nb + w+ 4] = t1;
    src[bh*NN + nb + w+ 8] = s2; dst[bh*NN + nb + w+ 8] = t2;
    src[bh*NN + nb + w+12] = s3; dst[bh*NN + nb + w+12] = t3;
  }
  __syncthreads();
  // coalesced hT write: tile mt = nt>>2, slots (nt&3)*16 .. +15
  int t = threadIdx.x;
  int dd = t >> 2, part = t & 3;
  _Float16* op = hT + (size_t)bh*DK*NN + (size_t)(nt>>2)*4096 + dd*64 + (nt&3)*16 + part*4;
  *(f16x4*)op = *(const f16x4*)&ls[dd][part*4];
}

// ---------------------------------------------------------------------------
// K2b: Mx[bh] = max_m dst[bh, m]
__global__ void __launch_bounds__(256) k_dmax(const float* __restrict__ dst,
                                              float* __restrict__ Mx){
  int bh = blockIdx.x; int t = threadIdx.x;
  float m = -INFINITY;
  for (int i = t; i < NN; i += 256) m = fmaxf(m, dst[bh*NN + i]);
  __shared__ float red[256];
  red[t] = m; __syncthreads();
  for (int o = 128; o >= 1; o >>= 1){ if (t < o) red[t] = fmaxf(red[t], red[t+o]); __syncthreads(); }
  if (t == 0) Mx[bh] = red[0];
}

// ---------------------------------------------------------------------------
// K3: MFMA attention, register A-fragment. Block = 32 rows; 4 waves = 4 k-chunks.
// Lane (w,lh,l5): row = l5, cols = w*16 + lh*8 + 0..7 of each 64-m tile.
// Scores -> f16 A-frag in regs -> 2 MFMAs (col halves). No P LDS round-trip.
__global__ void __launch_bounds__(256, 4) k_attn6(const float* __restrict__ src,
                                                  const float* __restrict__ dst,
                                                  const float* __restrict__ Mx,
                                                  const _Float16* __restrict__ hT,
                                                  const u64* __restrict__ maskT,
                                                  float* __restrict__ out){
  int rb = blockIdx.x & 63;
  int bh = blockIdx.x >> 6;
  int b  = bh >> 2;
  int n0 = rb * 32;
  int t = threadIdx.x;
  int w = t >> 6, l = t & 63;
  int lh = l >> 5, l5 = l & 31;

  // LDS: [0,16384) hs double buffer; [16384,24576) dstS; epilogue overlays all
  __shared__ __align__(16) char smem[27648];
  float* dstS = (float*)(smem + 16384);
  float* cs   = (float*)smem;            // epilogue: 3 waves x 64 lanes x 36 f32
  __shared__ float rs[4][32];

  // stage full dst row (2048 f32, 8KB)
  {
    const float* dp = dst + bh*NN;
    #pragma unroll
    for (int k = 0; k < 2; ++k){
      int i = (k*256 + t)*4;
      *(float4*)&dstS[i] = *(const float4*)&dp[i];
    }
  }
  float Mbh = Mx[bh];
  float srcv = src[bh*NN + n0 + l5];
  float bv = srcv + Mbh;
  float bnd = fmaxf(bv, 0.2f*bv);
  float psum = 0.f;
  f32x16 acc0 = {}, acc1 = {};

  const _Float16* gp = hT + (size_t)bh*DK*NN + (t>>2)*64 + (t&3)*16;
  int hb = (t>>2)*128 + (t&3)*32;
  int swz0 = SWZ(hb), swz1 = SWZ(hb+16);
  const u64* mrow = maskT + (size_t)(b*32)*NN + n0 + l5;
  int kb = w*16 + lh*8;                  // this lane's k-base within 64-m tile
  int bco = kb*2;                        // byte col offset for B reads

  // prologue: tile 0 -> LDS[0]; prefetch tile 1 into regs
  f16x8 rA = *(const f16x8*)gp;
  f16x8 rB = *(const f16x8*)(gp + 8);
  *(f16x8*)&smem[swz0] = rA;
  *(f16x8*)&smem[swz1] = rB;
  gp += 4096;
  rA = *(const f16x8*)gp;
  rB = *(const f16x8*)(gp + 8);
  __syncthreads();

  for (int mt = 0; mt < 32; ++mt){
    int cur = mt & 1;
    char* hsc = smem + cur*8192;
    char* hsn = smem + (cur^1)*8192;
    // write prefetched tile to next buffer; issue loads for tile mt+2
    if (mt < 31){
      *(f16x8*)&hsn[swz0] = rA;
      *(f16x8*)&hsn[swz1] = rB;
      if (mt < 30){
        gp += 4096;
        rA = *(const f16x8*)gp;
        rB = *(const f16x8*)(gp + 8);
      }
    }
    // mask bits + dst values for this lane's 8 cols
    u64 mk = mrow[(size_t)mt*NN];
    unsigned bits = (unsigned)(mk >> kb) & 0xFFu;
    float4 dv0 = *(const float4*)&dstS[mt*64 + kb];
    float4 dv1 = *(const float4*)&dstS[mt*64 + kb + 4];
    float dvals[8] = {dv0.x,dv0.y,dv0.z,dv0.w,dv1.x,dv1.y,dv1.z,dv1.w};
    // scores -> A-frag (registers)
    f16x8 A;
    #pragma unroll
    for (int i = 0; i < 8; ++i){
      float e = srcv + dvals[i];
      e = fmaxf(e, 0.2f*e);              // leaky (scaled domain)
      e = ((bits >> i) & 1u) ? e : NEGV;
      float p = fexp2(e - bnd);
      psum += p;
      A[i] = (_Float16)p;
    }
    // MFMA x2 on current buffer (col halves)
    f16x8 B0 = *(const f16x8*)&hsc[SWZ(l5*128 + bco)];
    f16x8 B1 = *(const f16x8*)&hsc[SWZ((32+l5)*128 + bco)];
    acc0 = __builtin_amdgcn_mfma_f32_32x32x16_f16(A, B0, acc0, 0, 0, 0);
    acc1 = __builtin_amdgcn_mfma_f32_32x32x16_f16(A, B1, acc1, 0, 0, 0);
    __syncthreads();
  }

  // row-sum partials: lane pair (l5, l5+32) both hold row l5 partials
  psum += __shfl_xor(psum, 32);
  if (l < 32) rs[w][l5] = psum;
  // k-partial accumulators: waves 1-3 dump to LDS (overlay; post-barrier safe)
  if (w){
    float* base = cs + (size_t)(w-1)*2304 + l*36;
    *(f32x16*)(base)      = acc0;
    *(f32x16*)(base + 16) = acc1;
  }
  __syncthreads();
  if (w == 0){
    #pragma unroll
    for (int ww = 0; ww < 3; ++ww){
      const float* base = cs + (size_t)ww*2304 + l*36;
      acc0 += *(const f32x16*)(base);
      acc1 += *(const f32x16*)(base + 16);
    }
    #pragma unroll
    for (int g = 0; g < 16; ++g){
      int row = (g & 3) + 8*(g >> 2) + 4*lh;
      float inv = 1.f / (rs[0][row] + rs[1][row] + rs[2][row] + rs[3][row]);
      size_t o = ((size_t)bh*NN + n0 + row)*DK;
      out[o + l5]      = acc0[g] * inv;
      out[o + 32 + l5] = acc1[g] * inv;
    }
  }
}

// ---------------------------------------------------------------------------
// K4: x[b,j,:] += elu(LN(x1[b,j,:])), x1 = reshape-reinterpret of att1
__global__ void __launch_bounds__(256) k_ln1(const float* __restrict__ att,
                                             const float* __restrict__ sc,
                                             const float* __restrict__ bi,
                                             float* __restrict__ x){
  int j = blockIdx.x & (NN-1);
  int b = blockIdx.x / NN;
  int c = threadIdx.x;
  int w = c >> 6, l = c & 63;
  int hh = j >> 9;
  int node = ((j & 511) << 2) + w;
  int d = c & 63;
  float v = att[(((size_t)(b*NH + hh)*NN) + node)*DK + d];
  __shared__ float red[8];
  float s = v;
  #pragma unroll
  for (int o = 32; o >= 1; o >>= 1) s += __shfl_xor(s, o);
  if (l == 0) red[w] = s;
  __syncthreads();
  float mu = (red[0]+red[1]+red[2]+red[3]) * (1.f/HD);
  float dv = v - mu;
  float q = dv*dv;
  #pragma unroll
  for (int o = 32; o >= 1; o >>= 1) q += __shfl_xor(q, o);
  if (l == 0) red[4+w] = q;
  __syncthreads();
  float var = (red[4]+red[5]+red[6]+red[7]) * (1.f/HD);
  float ln = dv * rsqrtf(var + 1e-5f) * sc[c] + bi[c];
  float el = (ln > 0.f) ? ln : (__expf(ln) - 1.f);
  x[(size_t)blockIdx.x*HD + c] += el;
}

// ---------------------------------------------------------------------------
// K5: out[b,n,d] = LN_64( mean_h att2[b,h,n,d] )
__global__ void __launch_bounds__(256) k_final(const float* __restrict__ att,
                                               const float* __restrict__ sc,
                                               const float* __restrict__ bi,
                                               float* __restrict__ out){
  int w = threadIdx.x >> 6; int d = threadIdx.x & 63;
  int bn = blockIdx.x*4 + w;
  int b = bn / NN; int n = bn & (NN-1);
  float v = 0.f;
  #pragma unroll
  for (int hh = 0; hh < NH; ++hh) v += att[((size_t)(b*NH + hh)*NN + n)*DK + d];
  v *= 0.25f;
  float s = v;
  #pragma unroll
  for (int o = 32; o >= 1; o >>= 1) s += __shfl_xor(s, o);
  float mu = s * (1.f/DK);
  float dv = v - mu;
  float q = dv*dv;
  #pragma unroll
  for (int o = 32; o >= 1; o >>= 1) q += __shfl_xor(q, o);
  float var = q * (1.f/DK);
  float ln = dv * rsqrtf(var + 1e-5f) * sc[d] + bi[d];
  out[(size_t)bn*DK + d] = ln;
}

// ---------------------------------------------------------------------------
extern "C" void kernel_launch(void* const* d_in, const int* in_sizes, int n_in,
                              void* d_out, int out_size, void* d_ws, size_t ws_size,
                              hipStream_t stream){
  const float* nf   = (const float*)d_in[0];
  const int*   adj  = (const int*)d_in[1];
  const float* Wp   = (const float*)d_in[2];
  const float* bp   = (const float*)d_in[3];
  const float* W1   = (const float*)d_in[4];
  const float* a1   = (const float*)d_in[5];
  const float* ln1s = (const float*)d_in[6];
  const float* ln1b = (const float*)d_in[7];
  const float* W2   = (const float*)d_in[8];
  const float* a2   = (const float*)d_in[9];
  const float* ln2s = (const float*)d_in[10];
  const float* ln2b = (const float*)d_in[11];

  float* ws   = (float*)d_ws;
  float* x    = ws;                      // 2,097,152 f32
  float* att  = ws + 2097152;            // 2,097,152 f32
  float* srcb = ws + 2*2097152;          // 32,768
  float* dstb = srcb + 32768;            // 32,768
  float* Mx   = dstb + 32768;            // 64 (pad)
  _Float16* hT = (_Float16*)(Mx + 64);   // 2,097,152 f16 = 4 MB
  u64* maskT = (u64*)(hT + 2097152);     // 262,144 u64 = 2 MB

  k_proj <<<BB*NN/16,     256, 0, stream>>>(nf, Wp, bp, x);
  k_mask <<<BB*NN/4,      256, 0, stream>>>(adj, maskT);
  k_head <<<BB*NH*NN/16,  256, 0, stream>>>(x, W1, a1, hT, srcb, dstb);
  k_dmax <<<BB*NH,        256, 0, stream>>>(dstb, Mx);
  k_attn6<<<BB*NH*NN/32,  256, 0, stream>>>(srcb, dstb, Mx, hT, maskT, att);
  k_ln1  <<<BB*NN,        256, 0, stream>>>(att, ln1s, ln1b, x);
  k_head <<<BB*NH*NN/16,  256, 0, stream>>>(x, W2, a2, hT, srcb, dstb);
  k_dmax <<<BB*NH,        256, 0, stream>>>(dstb, Mx);
  k_attn6<<<BB*NH*NN/32,  256, 0, stream>>>(srcb, dstb, Mx, hT, maskT, att);
  k_final<<<BB*NN/4,      256, 0, stream>>>(att, ln2s, ln2b, (float*)d_out);
}

// Round 8
// 179.154 us; speedup vs baseline: 7.4622x; 1.0350x over previous
//
#include <hip/hip_runtime.h>
#include <hip/hip_bf16.h>
#include <hip/hip_fp16.h>

// Shapes (fixed by the reference)
#define BB   4
#define NN   2048
#define FIN  128
#define HD   256
#define NH   4
#define DK   64
#define NEGV (-1000000000.0f)
#define LOG2E 1.4426950408889634f

typedef _Float16 f16x8 __attribute__((ext_vector_type(8)));
typedef _Float16 f16x4 __attribute__((ext_vector_type(4)));
typedef float    f32x16 __attribute__((ext_vector_type(16)));
typedef unsigned long long u64;

// XOR swizzle for 128B-pitch LDS rows
__device__ __forceinline__ int SWZ(int b){ return b ^ (((b >> 7) & 7) << 4); }
// XOR swizzle for 512B-pitch LDS rows
__device__ __forceinline__ int SWZ9(int b){ return b ^ (((b >> 9) & 7) << 4); }

__device__ __forceinline__ float fexp2(float x){
#if __has_builtin(__builtin_amdgcn_exp2f)
  return __builtin_amdgcn_exp2f(x);
#else
  return __exp2f(x);
#endif
}

__device__ __forceinline__ f16x8 pack8(float4 a, float4 b){
  f16x8 r;
  r[0]=(_Float16)a.x; r[1]=(_Float16)a.y; r[2]=(_Float16)a.z; r[3]=(_Float16)a.w;
  r[4]=(_Float16)b.x; r[5]=(_Float16)b.y; r[6]=(_Float16)b.z; r[7]=(_Float16)b.w;
  return r;
}

// ---------------------------------------------------------------------------
// K0: one-time prep: WT[layer][hh][d][k] f16 = W[layer][hh][k][d]; aS = a*LOG2E
__global__ void __launch_bounds__(256) k_prep(const float* __restrict__ W1,
                                              const float* __restrict__ a1,
                                              const float* __restrict__ W2,
                                              const float* __restrict__ a2,
                                              _Float16* __restrict__ WT,
                                              float* __restrict__ aS){
  int lay = blockIdx.x >> 2, hh = blockIdx.x & 3;
  const float* W = (lay ? W2 : W1) + (size_t)hh*HD*DK;
  const float* a = (lay ? a2 : a1) + (size_t)hh*2*DK;
  _Float16* wt = WT + ((size_t)lay*4 + hh)*64*256;
  float* as = aS + ((size_t)lay*4 + hh)*128;
  int t = threadIdx.x;
  int d = t & 63;
  #pragma unroll 4
  for (int it = 0; it < 64; ++it){
    int k = it*4 + (t >> 6);
    wt[(size_t)d*256 + k] = (_Float16)W[(size_t)k*DK + d];
  }
  if (t < 128) as[t] = a[t] * LOG2E;
}

// ---------------------------------------------------------------------------
// K1: x[b,n,c] = sum_i nf[b,n,i]*Wp[i,c] + bp[c]. 16 rows/block.
__global__ void __launch_bounds__(256) k_proj(const float* __restrict__ nf,
                                              const float* __restrict__ Wp,
                                              const float* __restrict__ bp,
                                              float* __restrict__ x){
  int r0 = blockIdx.x * 16;
  int c = threadIdx.x;
  __shared__ __align__(16) float xs[16][FIN];
  for (int k = threadIdx.x; k < 16*FIN/4; k += 256){
    int r = k >> 5; int cc = (k & 31) * 4;
    *(float4*)&xs[r][cc] = *(const float4*)&nf[(size_t)(r0 + r)*FIN + cc];
  }
  __syncthreads();
  float acc[16];
  float bv = bp[c];
  #pragma unroll
  for (int r = 0; r < 16; ++r) acc[r] = bv;
  #pragma unroll 4
  for (int i = 0; i < FIN; i += 4){
    float w0 = Wp[(i+0)*HD + c];
    float w1 = Wp[(i+1)*HD + c];
    float w2 = Wp[(i+2)*HD + c];
    float w3 = Wp[(i+3)*HD + c];
    #pragma unroll
    for (int r = 0; r < 16; ++r){
      float4 xv = *(const float4*)&xs[r][i];
      acc[r] = fmaf(xv.x, w0, acc[r]);
      acc[r] = fmaf(xv.y, w1, acc[r]);
      acc[r] = fmaf(xv.z, w2, acc[r]);
      acc[r] = fmaf(xv.w, w3, acc[r]);
    }
  }
  #pragma unroll
  for (int r = 0; r < 16; ++r) x[(size_t)(r0 + r)*HD + c] = acc[r];
}

// ---------------------------------------------------------------------------
// K1b: bitmask pack, TRANSPOSED: maskT[b][mt][n] = ballot over cols mt*64..+63
__global__ void __launch_bounds__(256) k_mask(const int* __restrict__ adj,
                                              u64* __restrict__ maskT){
  int w = threadIdx.x >> 6, lane = threadIdx.x & 63;
  int row = blockIdx.x*4 + w;
  int b = row >> 11, n = row & (NN-1);
  const int* ar = adj + (size_t)row*NN;
  #pragma unroll 4
  for (int mt = 0; mt < 32; ++mt){
    u64 bal = __ballot(ar[mt*64 + lane] != 0);
    if (lane == 0) maskT[(size_t)(b*32 + mt)*NN + n] = bal;
  }
}

// ---------------------------------------------------------------------------
// K2: MFMA head projection. Block = 64 rows of one (b,hh); 4 waves (2x2).
// A = x-tile f16 (swizzled LDS), B = WT f16 (swizzled LDS). K=256, 16 MFMA steps.
// Epilogue: hT via LDS-bounce transpose; src/dst via shuffle reduce; both written.
__global__ void __launch_bounds__(256) k_head3(const float* __restrict__ x,
                                               const _Float16* __restrict__ WT,
                                               const float* __restrict__ aS,
                                               _Float16* __restrict__ hT,
                                               float* __restrict__ src,
                                               float* __restrict__ dst){
  int nt = blockIdx.x & 31;
  int bh = blockIdx.x >> 5;
  int b = bh >> 2, hh = bh & 3;
  int n0 = nt * 64;
  int t = threadIdx.x;
  int w = t >> 6, l = t & 63, lh = l >> 5, l5 = l & 31;
  int wr = w >> 1, wc = w & 1;

  __shared__ __align__(16) char sm[66560];   // xa[0,32K) wt[32K,64K) sd[64K,+1K); ls overlays xa

  // stage x rows n0..n0+63 as f16 (swizzled, 512B pitch)
  {
    int r = t >> 2, ks = (t & 3) * 64;
    const float* xp = &x[((size_t)(b*NN) + n0 + r)*HD + ks];
    #pragma unroll
    for (int u = 0; u < 8; ++u){
      float4 v0 = *(const float4*)&xp[u*8];
      float4 v1 = *(const float4*)&xp[u*8 + 4];
      *(f16x8*)&sm[SWZ9(r*512 + (ks + u*8)*2)] = pack8(v0, v1);
    }
  }
  // stage WT[hh] (64 x 256 f16, swizzled)
  {
    int d = t >> 2, ks = (t & 3) * 64;
    const _Float16* wp = WT + ((size_t)hh*64 + d)*256 + ks;
    #pragma unroll
    for (int u = 0; u < 8; ++u){
      f16x8 v = *(const f16x8*)&wp[u*8];
      *(f16x8*)&sm[SWZ9(32768 + d*512 + (ks + u*8)*2)] = v;
    }
  }
  __syncthreads();

  f32x16 accA = {}, accB = {};
  #pragma unroll
  for (int kk = 0; kk < 16; kk += 2){
    int kb0 = (kk*16 + lh*8)*2;
    int kb1 = ((kk+1)*16 + lh*8)*2;
    f16x8 A0 = *(const f16x8*)&sm[SWZ9((wr*32 + l5)*512 + kb0)];
    f16x8 B0 = *(const f16x8*)&sm[SWZ9(32768 + (wc*32 + l5)*512 + kb0)];
    f16x8 A1 = *(const f16x8*)&sm[SWZ9((wr*32 + l5)*512 + kb1)];
    f16x8 B1 = *(const f16x8*)&sm[SWZ9(32768 + (wc*32 + l5)*512 + kb1)];
    accA = __builtin_amdgcn_mfma_f32_32x32x16_f16(A0, B0, accA, 0, 0, 0);
    accB = __builtin_amdgcn_mfma_f32_32x32x16_f16(A1, B1, accB, 0, 0, 0);
  }
  f32x16 acc = accA + accB;

  __syncthreads();   // xa dead; overlay ls
  _Float16* ls = (_Float16*)sm;        // [64 d][80 rows pad] f16 = 10240B
  int col = wc*32 + l5;
  float as = aS[((size_t)hh)*128 + col];
  float ad = aS[((size_t)hh)*128 + 64 + col];
  float* sd = (float*)(sm + 65536);    // [2][2][64] f32
  #pragma unroll
  for (int g = 0; g < 16; ++g){
    int row = wr*32 + (g & 3) + 8*(g >> 2) + 4*lh;
    ls[col*80 + row] = (_Float16)acc[g];
    float sv = acc[g] * as;
    float dv = acc[g] * ad;
    #pragma unroll
    for (int o = 16; o >= 1; o >>= 1){ sv += __shfl_xor(sv, o); dv += __shfl_xor(dv, o); }
    if (l5 == 0){
      sd[wc*64 + row]        = sv;
      sd[128 + wc*64 + row]  = dv;
    }
  }
  __syncthreads();
  // coalesced hT write
  int dd = t >> 2, part = t & 3;
  f16x8 o0 = *(const f16x8*)&ls[dd*80 + part*16];
  f16x8 o1 = *(const f16x8*)&ls[dd*80 + part*16 + 8];
  _Float16* op = hT + (size_t)bh*DK*NN + (size_t)nt*4096 + dd*64 + part*16;
  *(f16x8*)op = o0;
  *(f16x8*)(op + 8) = o1;
  if (t < 64){
    src[bh*NN + n0 + t] = sd[t] + sd[64 + t];
    dst[bh*NN + n0 + t] = sd[128 + t] + sd[192 + t];
  }
}

// ---------------------------------------------------------------------------
// K2b: Mx[bh] = max_m dst[bh, m]
__global__ void __launch_bounds__(256) k_dmax(const float* __restrict__ dst,
                                              float* __restrict__ Mx){
  int bh = blockIdx.x; int t = threadIdx.x;
  float m = -INFINITY;
  for (int i = t; i < NN; i += 256) m = fmaxf(m, dst[bh*NN + i]);
  __shared__ float red[256];
  red[t] = m; __syncthreads();
  for (int o = 128; o >= 1; o >>= 1){ if (t < o) red[t] = fmaxf(red[t], red[t+o]); __syncthreads(); }
  if (t == 0) Mx[bh] = red[0];
}

// ---------------------------------------------------------------------------
// K3: barrier-free MFMA attention. Block = 32 rows; 4 waves = 4 k-chunks.
// B-fragments read DIRECTLY from global hT (L2-resident). 1-deep prefetch.
__global__ void __launch_bounds__(256, 4) k_attn7(const float* __restrict__ src,
                                                  const float* __restrict__ dst,
                                                  const float* __restrict__ Mx,
                                                  const _Float16* __restrict__ hT,
                                                  const u64* __restrict__ maskT,
                                                  float* __restrict__ out){
  int rb = blockIdx.x & 63;
  int bh = blockIdx.x >> 6;
  int b  = bh >> 2;
  int n0 = rb * 32;
  int t = threadIdx.x;
  int w = t >> 6, l = t & 63;
  int lh = l >> 5, l5 = l & 31;

  __shared__ __align__(16) char smem[27648];
  float* dstS = (float*)smem;          // 8KB live during loop
  float* cs   = (float*)smem;          // epilogue overlay (post-barrier)
  __shared__ float rs[4][32];

  {
    const float* dp = dst + bh*NN;
    #pragma unroll
    for (int k = 0; k < 2; ++k){
      int i = (k*256 + t)*4;
      *(float4*)&dstS[i] = *(const float4*)&dp[i];
    }
  }
  float Mbh = Mx[bh];
  float srcv = src[bh*NN + n0 + l5];
  float bv = srcv + Mbh;
  float bnd = fmaxf(bv, 0.2f*bv);
  float psum = 0.f;
  f32x16 acc0 = {}, acc1 = {};

  int kb = w*16 + lh*8;
  const u64* mp = maskT + (size_t)(b*32)*NN + n0 + l5;
  const _Float16* gB = hT + (size_t)bh*DK*NN + l5*64 + kb;
  u64 mk = *mp;
  f16x8 B0 = *(const f16x8*)gB;
  f16x8 B1 = *(const f16x8*)(gB + 2048);
  __syncthreads();

  for (int mt = 0; mt < 32; ++mt){
    u64 mkN; f16x8 B0N, B1N;
    if (mt < 31){
      mp += NN; gB += 4096;
      mkN = *mp;
      B0N = *(const f16x8*)gB;
      B1N = *(const f16x8*)(gB + 2048);
    }
    float4 dv0 = *(const float4*)&dstS[mt*64 + kb];
    float4 dv1 = *(const float4*)&dstS[mt*64 + kb + 4];
    unsigned bits = (unsigned)(mk >> kb) & 0xFFu;
    float dvals[8] = {dv0.x,dv0.y,dv0.z,dv0.w,dv1.x,dv1.y,dv1.z,dv1.w};
    f16x8 A;
    #pragma unroll
    for (int i = 0; i < 8; ++i){
      float e = srcv + dvals[i];
      e = fmaxf(e, 0.2f*e);              // leaky (scaled domain)
      e = ((bits >> i) & 1u) ? e : NEGV;
      float p = fexp2(e - bnd);
      psum += p;
      A[i] = (_Float16)p;
    }
    acc0 = __builtin_amdgcn_mfma_f32_32x32x16_f16(A, B0, acc0, 0, 0, 0);
    acc1 = __builtin_amdgcn_mfma_f32_32x32x16_f16(A, B1, acc1, 0, 0, 0);
    mk = mkN; B0 = B0N; B1 = B1N;
  }

  // row-sum partials: lanes (l5, l5+32) are the same row
  psum += __shfl_xor(psum, 32);
  if (l < 32) rs[w][l5] = psum;
  __syncthreads();                     // dstS dead; cs overlay safe
  if (w){
    float* base = cs + (size_t)(w-1)*2304 + l*36;
    *(f32x16*)(base)      = acc0;
    *(f32x16*)(base + 16) = acc1;
  }
  __syncthreads();
  if (w == 0){
    #pragma unroll
    for (int ww = 0; ww < 3; ++ww){
      const float* base = cs + (size_t)ww*2304 + l*36;
      acc0 += *(const f32x16*)(base);
      acc1 += *(const f32x16*)(base + 16);
    }
    #pragma unroll
    for (int g = 0; g < 16; ++g){
      int row = (g & 3) + 8*(g >> 2) + 4*lh;
      float inv = 1.f / (rs[0][row] + rs[1][row] + rs[2][row] + rs[3][row]);
      size_t o = ((size_t)bh*NN + n0 + row)*DK;
      out[o + l5]      = acc0[g] * inv;
      out[o + 32 + l5] = acc1[g] * inv;
    }
  }
}

// ---------------------------------------------------------------------------
// K4: x[b,j,:] += elu(LN(x1[b,j,:])), x1 = reshape-reinterpret of att1
__global__ void __launch_bounds__(256) k_ln1(const float* __restrict__ att,
                                             const float* __restrict__ sc,
                                             const float* __restrict__ bi,
                                             float* __restrict__ x){
  int j = blockIdx.x & (NN-1);
  int b = blockIdx.x / NN;
  int c = threadIdx.x;
  int w = c >> 6, l = c & 63;
  int hh = j >> 9;
  int node = ((j & 511) << 2) + w;
  int d = c & 63;
  float v = att[(((size_t)(b*NH + hh)*NN) + node)*DK + d];
  __shared__ float red[8];
  float s = v;
  #pragma unroll
  for (int o = 32; o >= 1; o >>= 1) s += __shfl_xor(s, o);
  if (l == 0) red[w] = s;
  __syncthreads();
  float mu = (red[0]+red[1]+red[2]+red[3]) * (1.f/HD);
  float dv = v - mu;
  float q = dv*dv;
  #pragma unroll
  for (int o = 32; o >= 1; o >>= 1) q += __shfl_xor(q, o);
  if (l == 0) red[4+w] = q;
  __syncthreads();
  float var = (red[4]+red[5]+red[6]+red[7]) * (1.f/HD);
  float ln = dv * rsqrtf(var + 1e-5f) * sc[c] + bi[c];
  float el = (ln > 0.f) ? ln : (__expf(ln) - 1.f);
  x[(size_t)blockIdx.x*HD + c] += el;
}

// ---------------------------------------------------------------------------
// K5: out[b,n,d] = LN_64( mean_h att2[b,h,n,d] )
__global__ void __launch_bounds__(256) k_final(const float* __restrict__ att,
                                               const float* __restrict__ sc,
                                               const float* __restrict__ bi,
                                               float* __restrict__ out){
  int w = threadIdx.x >> 6; int d = threadIdx.x & 63;
  int bn = blockIdx.x*4 + w;
  int b = bn / NN; int n = bn & (NN-1);
  float v = 0.f;
  #pragma unroll
  for (int hh = 0; hh < NH; ++hh) v += att[((size_t)(b*NH + hh)*NN + n)*DK + d];
  v *= 0.25f;
  float s = v;
  #pragma unroll
  for (int o = 32; o >= 1; o >>= 1) s += __shfl_xor(s, o);
  float mu = s * (1.f/DK);
  float dv = v - mu;
  float q = dv*dv;
  #pragma unroll
  for (int o = 32; o >= 1; o >>= 1) q += __shfl_xor(q, o);
  float var = q * (1.f/DK);
  float ln = dv * rsqrtf(var + 1e-5f) * sc[d] + bi[d];
  out[(size_t)bn*DK + d] = ln;
}

// ---------------------------------------------------------------------------
extern "C" void kernel_launch(void* const* d_in, const int* in_sizes, int n_in,
                              void* d_out, int out_size, void* d_ws, size_t ws_size,
                              hipStream_t stream){
  const float* nf   = (const float*)d_in[0];
  const int*   adj  = (const int*)d_in[1];
  const float* Wp   = (const float*)d_in[2];
  const float* bp   = (const float*)d_in[3];
  const float* W1   = (const float*)d_in[4];
  const float* a1   = (const float*)d_in[5];
  const float* ln1s = (const float*)d_in[6];
  const float* ln1b = (const float*)d_in[7];
  const float* W2   = (const float*)d_in[8];
  const float* a2   = (const float*)d_in[9];
  const float* ln2s = (const float*)d_in[10];
  const float* ln2b = (const float*)d_in[11];

  float* ws   = (float*)d_ws;
  float* x    = ws;                      // 2,097,152 f32
  float* att  = ws + 2097152;            // 2,097,152 f32
  float* srcb = ws + 2*2097152;          // 32,768
  float* dstb = srcb + 32768;            // 32,768
  float* Mx   = dstb + 32768;            // 64 (pad)
  _Float16* hT = (_Float16*)(Mx + 64);   // 2,097,152 f16 = 4 MB
  u64* maskT  = (u64*)(hT + 2097152);    // 262,144 u64 = 2 MB
  _Float16* WT = (_Float16*)(maskT + 262144);   // 2*4*64*256 f16 = 512 KB
  float* aS   = (float*)(WT + 131072*2);        // 2*4*128 f32

  k_prep <<<8,            256, 0, stream>>>(W1, a1, W2, a2, WT, aS);
  k_proj <<<BB*NN/16,     256, 0, stream>>>(nf, Wp, bp, x);
  k_mask <<<BB*NN/4,      256, 0, stream>>>(adj, maskT);
  k_head3<<<BB*NH*NN/64,  256, 0, stream>>>(x, WT,          aS,          hT, srcb, dstb);
  k_dmax <<<BB*NH,        256, 0, stream>>>(dstb, Mx);
  k_attn7<<<BB*NH*NN/32,  256, 0, stream>>>(srcb, dstb, Mx, hT, maskT, att);
  k_ln1  <<<BB*NN,        256, 0, stream>>>(att, ln1s, ln1b, x);
  k_head3<<<BB*NH*NN/64,  256, 0, stream>>>(x, WT + 65536,  aS + 512,    hT, srcb, dstb);
  k_dmax <<<BB*NH,        256, 0, stream>>>(dstb, Mx);
  k_attn7<<<BB*NH*NN/32,  256, 0, stream>>>(srcb, dstb, Mx, hT, maskT, att);
  k_final<<<BB*NN/4,      256, 0, stream>>>(att, ln2s, ln2b, (float*)d_out);
}

// Round 10
// 151.619 us; speedup vs baseline: 8.8174x; 1.1816x over previous
//
#include <hip/hip_runtime.h>
#include <hip/hip_bf16.h>
#include <hip/hip_fp16.h>

// Shapes (fixed by the reference)
#define BB   4
#define NN   2048
#define FIN  128
#define HD   256
#define NH   4
#define DK   64
#define NEGV (-1000000000.0f)
#define LOG2E 1.4426950408889634f

typedef _Float16 f16x8 __attribute__((ext_vector_type(8)));
typedef float    f32x16 __attribute__((ext_vector_type(16)));
typedef unsigned long long u64;

// XOR swizzle for 512B-pitch LDS rows
__device__ __forceinline__ int SWZ9(int b){ return b ^ (((b >> 9) & 7) << 4); }

__device__ __forceinline__ float fexp2(float x){
#if __has_builtin(__builtin_amdgcn_exp2f)
  return __builtin_amdgcn_exp2f(x);
#else
  return __exp2f(x);
#endif
}

__device__ __forceinline__ f16x8 pack8(float4 a, float4 b){
  f16x8 r;
  r[0]=(_Float16)a.x; r[1]=(_Float16)a.y; r[2]=(_Float16)a.z; r[3]=(_Float16)a.w;
  r[4]=(_Float16)b.x; r[5]=(_Float16)b.y; r[6]=(_Float16)b.z; r[7]=(_Float16)b.w;
  return r;
}

// ---------------------------------------------------------------------------
// K0: one-time prep: WT[layer][hh][d][k] f16 = W[layer][hh][k][d]; aS = a*LOG2E
__global__ void __launch_bounds__(256) k_prep(const float* __restrict__ W1,
                                              const float* __restrict__ a1,
                                              const float* __restrict__ W2,
                                              const float* __restrict__ a2,
                                              _Float16* __restrict__ WT,
                                              float* __restrict__ aS){
  int lay = blockIdx.x >> 2, hh = blockIdx.x & 3;
  const float* W = (lay ? W2 : W1) + (size_t)hh*HD*DK;
  const float* a = (lay ? a2 : a1) + (size_t)hh*2*DK;
  _Float16* wt = WT + ((size_t)lay*4 + hh)*64*256;
  float* as = aS + ((size_t)lay*4 + hh)*128;
  int t = threadIdx.x;
  int d = t & 63;
  #pragma unroll 4
  for (int it = 0; it < 64; ++it){
    int k = it*4 + (t >> 6);
    wt[(size_t)d*256 + k] = (_Float16)W[(size_t)k*DK + d];
  }
  if (t < 128) as[t] = a[t] * LOG2E;
}

// ---------------------------------------------------------------------------
// K1: x[b,n,c] = sum_i nf[b,n,i]*Wp[i,c] + bp[c]. 16 rows/block.
__global__ void __launch_bounds__(256) k_proj(const float* __restrict__ nf,
                                              const float* __restrict__ Wp,
                                              const float* __restrict__ bp,
                                              float* __restrict__ x){
  int r0 = blockIdx.x * 16;
  int c = threadIdx.x;
  __shared__ __align__(16) float xs[16][FIN];
  for (int k = threadIdx.x; k < 16*FIN/4; k += 256){
    int r = k >> 5; int cc = (k & 31) * 4;
    *(float4*)&xs[r][cc] = *(const float4*)&nf[(size_t)(r0 + r)*FIN + cc];
  }
  __syncthreads();
  float acc[16];
  float bv = bp[c];
  #pragma unroll
  for (int r = 0; r < 16; ++r) acc[r] = bv;
  #pragma unroll 4
  for (int i = 0; i < FIN; i += 4){
    float w0 = Wp[(i+0)*HD + c];
    float w1 = Wp[(i+1)*HD + c];
    float w2 = Wp[(i+2)*HD + c];
    float w3 = Wp[(i+3)*HD + c];
    #pragma unroll
    for (int r = 0; r < 16; ++r){
      float4 xv = *(const float4*)&xs[r][i];
      acc[r] = fmaf(xv.x, w0, acc[r]);
      acc[r] = fmaf(xv.y, w1, acc[r]);
      acc[r] = fmaf(xv.z, w2, acc[r]);
      acc[r] = fmaf(xv.w, w3, acc[r]);
    }
  }
  #pragma unroll
  for (int r = 0; r < 16; ++r) x[(size_t)(r0 + r)*HD + c] = acc[r];
}

// ---------------------------------------------------------------------------
// K1b: bitmask pack, TRANSPOSED: maskT[b][mt][n] = ballot over cols mt*64..+63
__global__ void __launch_bounds__(256) k_mask(const int* __restrict__ adj,
                                              u64* __restrict__ maskT){
  int w = threadIdx.x >> 6, lane = threadIdx.x & 63;
  int row = blockIdx.x*4 + w;
  int b = row >> 11, n = row & (NN-1);
  const int* ar = adj + (size_t)row*NN;
  #pragma unroll 4
  for (int mt = 0; mt < 32; ++mt){
    u64 bal = __ballot(ar[mt*64 + lane] != 0);
    if (lane == 0) maskT[(size_t)(b*32 + mt)*NN + n] = bal;
  }
}

// ---------------------------------------------------------------------------
// K2: MFMA head projection. Block = 64 rows of one (b,hh); 4 waves (2x2).
// Epilogue writes hT in MFMA B-FRAGMENT ORDER:
//   tile[nt] flat idx = kc*1024 + dh*512 + l5*16 + lh*8 + e
//   where m = kc*16 + lh*8 + e (local node within 64), d = dh*32 + l5.
__global__ void __launch_bounds__(256) k_head3(const float* __restrict__ x,
                                               const _Float16* __restrict__ WT,
                                               const float* __restrict__ aS,
                                               _Float16* __restrict__ hT,
                                               float* __restrict__ src,
                                               float* __restrict__ dst){
  int nt = blockIdx.x & 31;
  int bh = blockIdx.x >> 5;
  int b = bh >> 2, hh = bh & 3;
  int n0 = nt * 64;
  int t = threadIdx.x;
  int w = t >> 6, l = t & 63, lh = l >> 5, l5 = l & 31;
  int wr = w >> 1, wc = w & 1;

  __shared__ __align__(16) char sm[66560];   // xa[0,32K) wt[32K,64K) sd[64K,+1K); ls overlays xa

  {
    int r = t >> 2, ks = (t & 3) * 64;
    const float* xp = &x[((size_t)(b*NN) + n0 + r)*HD + ks];
    #pragma unroll
    for (int u = 0; u < 8; ++u){
      float4 v0 = *(const float4*)&xp[u*8];
      float4 v1 = *(const float4*)&xp[u*8 + 4];
      *(f16x8*)&sm[SWZ9(r*512 + (ks + u*8)*2)] = pack8(v0, v1);
    }
  }
  {
    int d = t >> 2, ks = (t & 3) * 64;
    const _Float16* wp = WT + ((size_t)hh*64 + d)*256 + ks;
    #pragma unroll
    for (int u = 0; u < 8; ++u){
      f16x8 v = *(const f16x8*)&wp[u*8];
      *(f16x8*)&sm[SWZ9(32768 + d*512 + (ks + u*8)*2)] = v;
    }
  }
  __syncthreads();

  f32x16 accA = {}, accB = {};
  #pragma unroll
  for (int kk = 0; kk < 16; kk += 2){
    int kb0 = (kk*16 + lh*8)*2;
    int kb1 = ((kk+1)*16 + lh*8)*2;
    f16x8 A0 = *(const f16x8*)&sm[SWZ9((wr*32 + l5)*512 + kb0)];
    f16x8 B0 = *(const f16x8*)&sm[SWZ9(32768 + (wc*32 + l5)*512 + kb0)];
    f16x8 A1 = *(const f16x8*)&sm[SWZ9((wr*32 + l5)*512 + kb1)];
    f16x8 B1 = *(const f16x8*)&sm[SWZ9(32768 + (wc*32 + l5)*512 + kb1)];
    accA = __builtin_amdgcn_mfma_f32_32x32x16_f16(A0, B0, accA, 0, 0, 0);
    accB = __builtin_amdgcn_mfma_f32_32x32x16_f16(A1, B1, accB, 0, 0, 0);
  }
  f32x16 acc = accA + accB;

  __syncthreads();   // xa dead; overlay ls
  _Float16* ls = (_Float16*)sm;        // [64 d][80 rows pad] f16
  int col = wc*32 + l5;
  float as = aS[((size_t)hh)*128 + col];
  float ad = aS[((size_t)hh)*128 + 64 + col];
  float* sd = (float*)(sm + 65536);    // [2][2][64] f32
  #pragma unroll
  for (int g = 0; g < 16; ++g){
    int row = wr*32 + (g & 3) + 8*(g >> 2) + 4*lh;
    ls[col*80 + row] = (_Float16)acc[g];
    float sv = acc[g] * as;
    float dv = acc[g] * ad;
    #pragma unroll
    for (int o = 16; o >= 1; o >>= 1){ sv += __shfl_xor(sv, o); dv += __shfl_xor(dv, o); }
    if (l5 == 0){
      sd[wc*64 + row]        = sv;
      sd[128 + wc*64 + row]  = dv;
    }
  }
  __syncthreads();
  int dd = t >> 2, part = t & 3;
  f16x8 o0 = *(const f16x8*)&ls[dd*80 + part*16];
  f16x8 o1 = *(const f16x8*)&ls[dd*80 + part*16 + 8];
  int base = part*1024 + (dd >> 5)*512 + (dd & 31)*16;
  _Float16* op = hT + (size_t)bh*131072 + (size_t)nt*4096 + base;
  *(f16x8*)op = o0;
  *(f16x8*)(op + 8) = o1;
  if (t < 64){
    src[bh*NN + n0 + t] = sd[t] + sd[64 + t];
    dst[bh*NN + n0 + t] = sd[128 + t] + sd[192 + t];
  }
}

// ---------------------------------------------------------------------------
// K3: MFMA attention, m-split. Block = 32 rows x 1024 cols (half ms); 4 waves =
// 4 k-chunks. B from fragment-ordered hT (coalesced 1KB wave loads). Writes
// UNNORMALIZED acc half + partial psum; consumers normalize.
// Epilogue: SEQUENTIAL cross-wave combine through one 9.2KB LDS region
// (round-9 bug: parallel dump needed 27.6KB and overflowed the 9.7KB buffer).
__global__ void __launch_bounds__(256, 6) k_attn8(const float* __restrict__ src,
                                                  const float* __restrict__ dst,
                                                  const _Float16* __restrict__ hT,
                                                  const u64* __restrict__ maskT,
                                                  float* __restrict__ accB,
                                                  float* __restrict__ psB){
  int ms = blockIdx.x & 1;
  int rb = (blockIdx.x >> 1) & 63;
  int bh = blockIdx.x >> 7;
  int b  = bh >> 2;
  int n0 = rb * 32;
  int t = threadIdx.x;
  int w = t >> 6, l = t & 63;
  int lh = l >> 5, l5 = l & 31;

  __shared__ __align__(16) char smem[9728];    // dstS 4KB in loop; cs 9.2KB epilogue
  __shared__ float rs[4][32];
  __shared__ float red[4];
  float* dstS = (float*)smem;
  float* cs   = (float*)smem;

  {
    const float* dp = dst + bh*NN;
    float4 a = *(const float4*)&dp[t*4];
    float4 bq = *(const float4*)&dp[1024 + t*4];
    float mloc = fmaxf(fmaxf(fmaxf(a.x,a.y), fmaxf(a.z,a.w)),
                       fmaxf(fmaxf(bq.x,bq.y), fmaxf(bq.z,bq.w)));
    *(float4*)&dstS[t*4] = ms ? bq : a;
    #pragma unroll
    for (int o = 32; o >= 1; o >>= 1) mloc = fmaxf(mloc, __shfl_xor(mloc, o));
    if (l == 0) red[w] = mloc;
  }
  __syncthreads();
  float Mbh = fmaxf(fmaxf(red[0], red[1]), fmaxf(red[2], red[3]));
  float srcv = src[bh*NN + n0 + l5];
  float bv = srcv + Mbh;
  float bnd = fmaxf(bv, 0.2f*bv);
  float psum = 0.f;
  f32x16 acc0 = {}, acc1 = {};

  int kb = w*16 + lh*8;
  const u64* mp = maskT + (size_t)(b*32 + ms*16)*NN + n0 + l5;
  const char* gB = (const char*)hT + (size_t)bh*262144 + ms*131072
                   + w*2048 + l5*32 + lh*16;
  u64 mk = *mp;
  f16x8 B0 = *(const f16x8*)gB;
  f16x8 B1 = *(const f16x8*)(gB + 1024);
  float4 dq0 = *(const float4*)&dstS[kb];
  float4 dq1 = *(const float4*)&dstS[kb + 4];

  for (int mt = 0; mt < 16; ++mt){
    u64 mkN = mk; f16x8 B0N = B0, B1N = B1; float4 dq0N = dq0, dq1N = dq1;
    if (mt < 15){
      mp += NN; gB += 8192;
      mkN = *mp;
      B0N = *(const f16x8*)gB;
      B1N = *(const f16x8*)(gB + 1024);
      dq0N = *(const float4*)&dstS[(mt+1)*64 + kb];
      dq1N = *(const float4*)&dstS[(mt+1)*64 + kb + 4];
    }
    unsigned bits = (unsigned)(mk >> kb) & 0xFFu;
    float dvals[8] = {dq0.x,dq0.y,dq0.z,dq0.w,dq1.x,dq1.y,dq1.z,dq1.w};
    f16x8 A;
    #pragma unroll
    for (int i = 0; i < 8; ++i){
      float e = srcv + dvals[i];
      e = fmaxf(e, 0.2f*e);              // leaky (log2-scaled domain)
      e = ((bits >> i) & 1u) ? e : NEGV;
      float p = fexp2(e - bnd);
      psum += p;
      A[i] = (_Float16)p;
    }
    acc0 = __builtin_amdgcn_mfma_f32_32x32x16_f16(A, B0, acc0, 0, 0, 0);
    acc1 = __builtin_amdgcn_mfma_f32_32x32x16_f16(A, B1, acc1, 0, 0, 0);
    mk = mkN; B0 = B0N; B1 = B1N; dq0 = dq0N; dq1 = dq1N;
  }

  psum += __shfl_xor(psum, 32);
  if (l < 32) rs[w][l5] = psum;
  __syncthreads();                       // dstS dead; cs overlay safe
  float* accO = accB + (size_t)ms*2097152;
  float* psO  = psB + (size_t)ms*32768;
  if (t < 32) psO[bh*NN + n0 + t] = rs[0][t] + rs[1][t] + rs[2][t] + rs[3][t];
  // sequential cross-wave combine (fits 9.2KB: 64 lanes x 36 floats)
  #pragma unroll 1
  for (int ww = 1; ww < 4; ++ww){
    if (w == ww){
      float* base = cs + l*36;
      *(f32x16*)(base)      = acc0;
      *(f32x16*)(base + 16) = acc1;
    }
    __syncthreads();
    if (w == 0){
      const float* base = cs + l*36;
      acc0 += *(const f32x16*)(base);
      acc1 += *(const f32x16*)(base + 16);
    }
    __syncthreads();
  }
  if (w == 0){
    #pragma unroll
    for (int g = 0; g < 16; ++g){
      int row = (g & 3) + 8*(g >> 2) + 4*lh;
      size_t o = ((size_t)bh*NN + n0 + row)*DK;
      accO[o + l5]      = acc0[g];
      accO[o + 32 + l5] = acc1[g];
    }
  }
}

// ---------------------------------------------------------------------------
// K4: x[b,j,:] += elu(LN(x1[b,j,:])); x1 = reshape-reinterpret of att1,
// normalization (m-split halves / psum) folded in.
__global__ void __launch_bounds__(256) k_ln1(const float* __restrict__ a0,
                                             const float* __restrict__ a1,
                                             const float* __restrict__ p0,
                                             const float* __restrict__ p1,
                                             const float* __restrict__ sc,
                                             const float* __restrict__ bi,
                                             float* __restrict__ x){
  int j = blockIdx.x & (NN-1);
  int b = blockIdx.x / NN;
  int c = threadIdx.x;
  int w = c >> 6, l = c & 63;
  int hh = j >> 9;
  int node = ((j & 511) << 2) + w;
  size_t ridx = (size_t)(b*NH + hh)*NN + node;
  float inv = 1.f / (p0[ridx] + p1[ridx]);
  size_t idx = ridx*DK + l;
  float v = (a0[idx] + a1[idx]) * inv;
  __shared__ float red[8];
  float s = v;
  #pragma unroll
  for (int o = 32; o >= 1; o >>= 1) s += __shfl_xor(s, o);
  if (l == 0) red[w] = s;
  __syncthreads();
  float mu = (red[0]+red[1]+red[2]+red[3]) * (1.f/HD);
  float dv = v - mu;
  float q = dv*dv;
  #pragma unroll
  for (int o = 32; o >= 1; o >>= 1) q += __shfl_xor(q, o);
  if (l == 0) red[4+w] = q;
  __syncthreads();
  float var = (red[4]+red[5]+red[6]+red[7]) * (1.f/HD);
  float ln = dv * rsqrtf(var + 1e-5f) * sc[c] + bi[c];
  float el = (ln > 0.f) ? ln : (__expf(ln) - 1.f);
  x[(size_t)blockIdx.x*HD + c] += el;
}

// ---------------------------------------------------------------------------
// K5: out[b,n,d] = LN_64( mean_h att2[b,h,n,d] ), normalization folded in
__global__ void __launch_bounds__(256) k_final(const float* __restrict__ a0,
                                               const float* __restrict__ a1,
                                               const float* __restrict__ p0,
                                               const float* __restrict__ p1,
                                               const float* __restrict__ sc,
                                               const float* __restrict__ bi,
                                               float* __restrict__ out){
  int w = threadIdx.x >> 6; int d = threadIdx.x & 63;
  int bn = blockIdx.x*4 + w;
  int b = bn / NN; int n = bn & (NN-1);
  float v = 0.f;
  #pragma unroll
  for (int hh = 0; hh < NH; ++hh){
    size_t ridx = (size_t)(b*NH + hh)*NN + n;
    float inv = 1.f / (p0[ridx] + p1[ridx]);
    size_t idx = ridx*DK + d;
    v += (a0[idx] + a1[idx]) * inv;
  }
  v *= 0.25f;
  float s = v;
  #pragma unroll
  for (int o = 32; o >= 1; o >>= 1) s += __shfl_xor(s, o);
  float mu = s * (1.f/DK);
  float dv = v - mu;
  float q = dv*dv;
  #pragma unroll
  for (int o = 32; o >= 1; o >>= 1) q += __shfl_xor(q, o);
  float var = q * (1.f/DK);
  float ln = dv * rsqrtf(var + 1e-5f) * sc[d] + bi[d];
  out[(size_t)bn*DK + d] = ln;
}

// ---------------------------------------------------------------------------
extern "C" void kernel_launch(void* const* d_in, const int* in_sizes, int n_in,
                              void* d_out, int out_size, void* d_ws, size_t ws_size,
                              hipStream_t stream){
  const float* nf   = (const float*)d_in[0];
  const int*   adj  = (const int*)d_in[1];
  const float* Wp   = (const float*)d_in[2];
  const float* bp   = (const float*)d_in[3];
  const float* W1   = (const float*)d_in[4];
  const float* a1   = (const float*)d_in[5];
  const float* ln1s = (const float*)d_in[6];
  const float* ln1b = (const float*)d_in[7];
  const float* W2   = (const float*)d_in[8];
  const float* a2   = (const float*)d_in[9];
  const float* ln2s = (const float*)d_in[10];
  const float* ln2b = (const float*)d_in[11];

  float* ws   = (float*)d_ws;
  float* x    = ws;                        // 2,097,152 f32
  float* accA = ws + 2097152;              // 2 x 2,097,152 f32 (m-split halves)
  float* srcb = ws + 3*2097152;            // 32,768
  float* dstb = srcb + 32768;              // 32,768
  float* psA  = dstb + 32768;              // 2 x 32,768
  _Float16* hT = (_Float16*)(psA + 2*32768);  // 2,097,152 f16 = 4 MB
  u64* maskT  = (u64*)(hT + 2097152);      // 262,144 u64 = 2 MB
  _Float16* WT = (_Float16*)(maskT + 262144); // 131,072 f16 = 256 KB
  float* aS   = (float*)(WT + 131072);        // 1024 f32

  float* accH0 = accA;                 // half ms=0
  float* accH1 = accA + 2097152;       // half ms=1
  float* psH0  = psA;
  float* psH1  = psA + 32768;

  k_prep <<<8,            256, 0, stream>>>(W1, a1, W2, a2, WT, aS);
  k_proj <<<BB*NN/16,     256, 0, stream>>>(nf, Wp, bp, x);
  k_mask <<<BB*NN/4,      256, 0, stream>>>(adj, maskT);
  k_head3<<<BB*NH*NN/64,  256, 0, stream>>>(x, WT,         aS,       hT, srcb, dstb);
  k_attn8<<<BB*NH*NN/16,  256, 0, stream>>>(srcb, dstb, hT, maskT, accA, psA);
  k_ln1  <<<BB*NN,        256, 0, stream>>>(accH0, accH1, psH0, psH1, ln1s, ln1b, x);
  k_head3<<<BB*NH*NN/64,  256, 0, stream>>>(x, WT + 65536, aS + 512, hT, srcb, dstb);
  k_attn8<<<BB*NH*NN/16,  256, 0, stream>>>(srcb, dstb, hT, maskT, accA, psA);
  k_final<<<BB*NN/4,      256, 0, stream>>>(accH0, accH1, psH0, psH1, ln2s, ln2b, (float*)d_out);
}

// Round 11
// 137.608 us; speedup vs baseline: 9.7151x; 1.1018x over previous
//
#include <hip/hip_runtime.h>
#include <hip/hip_bf16.h>
#include <hip/hip_fp16.h>

// Shapes (fixed by the reference)
#define BB   4
#define NN   2048
#define FIN  128
#define HD   256
#define NH   4
#define DK   64
#define NEGV (-1000000000.0f)
#define LOG2E 1.4426950408889634f

typedef _Float16 f16x8 __attribute__((ext_vector_type(8)));
typedef float    f32x16 __attribute__((ext_vector_type(16)));
typedef unsigned long long u64;

// XOR swizzle for 512B-pitch LDS rows
__device__ __forceinline__ int SWZ9(int b){ return b ^ (((b >> 9) & 7) << 4); }

__device__ __forceinline__ float fexp2(float x){
#if __has_builtin(__builtin_amdgcn_exp2f)
  return __builtin_amdgcn_exp2f(x);
#else
  return __exp2f(x);
#endif
}

__device__ __forceinline__ f16x8 pack8(float4 a, float4 b){
  f16x8 r;
  r[0]=(_Float16)a.x; r[1]=(_Float16)a.y; r[2]=(_Float16)a.z; r[3]=(_Float16)a.w;
  r[4]=(_Float16)b.x; r[5]=(_Float16)b.y; r[6]=(_Float16)b.z; r[7]=(_Float16)b.w;
  return r;
}

// ---------------------------------------------------------------------------
// K_setup: fused independent preprocessing.
//   blocks [0,512):    x = nf@Wp + bp   (16 rows/block)
//   blocks [512,2560): maskT[b][mt][n] bitmask pack (4 rows/block)
//   blocks [2560,2568): WT f16 transpose + aS = a*LOG2E
__global__ void __launch_bounds__(256) k_setup(const float* __restrict__ nf,
                                               const float* __restrict__ Wp,
                                               const float* __restrict__ bp,
                                               const int* __restrict__ adj,
                                               const float* __restrict__ W1,
                                               const float* __restrict__ a1,
                                               const float* __restrict__ W2,
                                               const float* __restrict__ a2,
                                               float* __restrict__ x,
                                               u64* __restrict__ maskT,
                                               _Float16* __restrict__ WT,
                                               float* __restrict__ aS){
  __shared__ __align__(16) float xs[16][FIN];
  int bid = blockIdx.x;
  if (bid < 512){
    int r0 = bid * 16;
    int c = threadIdx.x;
    for (int k = threadIdx.x; k < 16*FIN/4; k += 256){
      int r = k >> 5; int cc = (k & 31) * 4;
      *(float4*)&xs[r][cc] = *(const float4*)&nf[(size_t)(r0 + r)*FIN + cc];
    }
    __syncthreads();
    float acc[16];
    float bv = bp[c];
    #pragma unroll
    for (int r = 0; r < 16; ++r) acc[r] = bv;
    #pragma unroll 4
    for (int i = 0; i < FIN; i += 4){
      float w0 = Wp[(i+0)*HD + c];
      float w1 = Wp[(i+1)*HD + c];
      float w2 = Wp[(i+2)*HD + c];
      float w3 = Wp[(i+3)*HD + c];
      #pragma unroll
      for (int r = 0; r < 16; ++r){
        float4 xv = *(const float4*)&xs[r][i];
        acc[r] = fmaf(xv.x, w0, acc[r]);
        acc[r] = fmaf(xv.y, w1, acc[r]);
        acc[r] = fmaf(xv.z, w2, acc[r]);
        acc[r] = fmaf(xv.w, w3, acc[r]);
      }
    }
    #pragma unroll
    for (int r = 0; r < 16; ++r) x[(size_t)(r0 + r)*HD + c] = acc[r];
  } else if (bid < 2560){
    int w = threadIdx.x >> 6, lane = threadIdx.x & 63;
    int row = (bid - 512)*4 + w;
    int b = row >> 11, n = row & (NN-1);
    const int* ar = adj + (size_t)row*NN;
    #pragma unroll 4
    for (int mt = 0; mt < 32; ++mt){
      u64 bal = __ballot(ar[mt*64 + lane] != 0);
      if (lane == 0) maskT[(size_t)(b*32 + mt)*NN + n] = bal;
    }
  } else {
    int q = bid - 2560;
    int lay = q >> 2, hh = q & 3;
    const float* W = (lay ? W2 : W1) + (size_t)hh*HD*DK;
    const float* a = (lay ? a2 : a1) + (size_t)hh*2*DK;
    _Float16* wt = WT + ((size_t)lay*4 + hh)*64*256;
    float* as = aS + ((size_t)lay*4 + hh)*128;
    int t = threadIdx.x;
    int d = t & 63;
    #pragma unroll 4
    for (int it = 0; it < 64; ++it){
      int k = it*4 + (t >> 6);
      wt[(size_t)d*256 + k] = (_Float16)W[(size_t)k*DK + d];
    }
    if (t < 128) as[t] = a[t] * LOG2E;
  }
}

// ---------------------------------------------------------------------------
// K2: MFMA head projection. Block = 64 rows of one (b,hh); 4 waves (2x2).
// Epilogue writes hT in MFMA B-FRAGMENT ORDER:
//   tile[nt] flat idx = kc*1024 + dh*512 + l5*16 + lh*8 + e
//   where m = kc*16 + lh*8 + e (local node within 64), d = dh*32 + l5.
__global__ void __launch_bounds__(256) k_head3(const float* __restrict__ x,
                                               const _Float16* __restrict__ WT,
                                               const float* __restrict__ aS,
                                               _Float16* __restrict__ hT,
                                               float* __restrict__ src,
                                               float* __restrict__ dst){
  int nt = blockIdx.x & 31;
  int bh = blockIdx.x >> 5;
  int b = bh >> 2, hh = bh & 3;
  int n0 = nt * 64;
  int t = threadIdx.x;
  int w = t >> 6, l = t & 63, lh = l >> 5, l5 = l & 31;
  int wr = w >> 1, wc = w & 1;

  __shared__ __align__(16) char sm[66560];   // xa[0,32K) wt[32K,64K) sd[64K,+1K); ls overlays xa

  {
    int r = t >> 2, ks = (t & 3) * 64;
    const float* xp = &x[((size_t)(b*NN) + n0 + r)*HD + ks];
    #pragma unroll
    for (int u = 0; u < 8; ++u){
      float4 v0 = *(const float4*)&xp[u*8];
      float4 v1 = *(const float4*)&xp[u*8 + 4];
      *(f16x8*)&sm[SWZ9(r*512 + (ks + u*8)*2)] = pack8(v0, v1);
    }
  }
  {
    int d = t >> 2, ks = (t & 3) * 64;
    const _Float16* wp = WT + ((size_t)hh*64 + d)*256 + ks;
    #pragma unroll
    for (int u = 0; u < 8; ++u){
      f16x8 v = *(const f16x8*)&wp[u*8];
      *(f16x8*)&sm[SWZ9(32768 + d*512 + (ks + u*8)*2)] = v;
    }
  }
  __syncthreads();

  f32x16 accA = {}, accB = {};
  #pragma unroll
  for (int kk = 0; kk < 16; kk += 2){
    int kb0 = (kk*16 + lh*8)*2;
    int kb1 = ((kk+1)*16 + lh*8)*2;
    f16x8 A0 = *(const f16x8*)&sm[SWZ9((wr*32 + l5)*512 + kb0)];
    f16x8 B0 = *(const f16x8*)&sm[SWZ9(32768 + (wc*32 + l5)*512 + kb0)];
    f16x8 A1 = *(const f16x8*)&sm[SWZ9((wr*32 + l5)*512 + kb1)];
    f16x8 B1 = *(const f16x8*)&sm[SWZ9(32768 + (wc*32 + l5)*512 + kb1)];
    accA = __builtin_amdgcn_mfma_f32_32x32x16_f16(A0, B0, accA, 0, 0, 0);
    accB = __builtin_amdgcn_mfma_f32_32x32x16_f16(A1, B1, accB, 0, 0, 0);
  }
  f32x16 acc = accA + accB;

  __syncthreads();   // xa dead; overlay ls
  _Float16* ls = (_Float16*)sm;        // [64 d][80 rows pad] f16
  int col = wc*32 + l5;
  float as = aS[((size_t)hh)*128 + col];
  float ad = aS[((size_t)hh)*128 + 64 + col];
  float* sd = (float*)(sm + 65536);    // [2][2][64] f32
  #pragma unroll
  for (int g = 0; g < 16; ++g){
    int row = wr*32 + (g & 3) + 8*(g >> 2) + 4*lh;
    ls[col*80 + row] = (_Float16)acc[g];
    float sv = acc[g] * as;
    float dv = acc[g] * ad;
    #pragma unroll
    for (int o = 16; o >= 1; o >>= 1){ sv += __shfl_xor(sv, o); dv += __shfl_xor(dv, o); }
    if (l5 == 0){
      sd[wc*64 + row]        = sv;
      sd[128 + wc*64 + row]  = dv;
    }
  }
  __syncthreads();
  int dd = t >> 2, part = t & 3;
  f16x8 o0 = *(const f16x8*)&ls[dd*80 + part*16];
  f16x8 o1 = *(const f16x8*)&ls[dd*80 + part*16 + 8];
  int base = part*1024 + (dd >> 5)*512 + (dd & 31)*16;
  _Float16* op = hT + (size_t)bh*131072 + (size_t)nt*4096 + base;
  *(f16x8*)op = o0;
  *(f16x8*)(op + 8) = o1;
  if (t < 64){
    src[bh*NN + n0 + t] = sd[t] + sd[64 + t];
    dst[bh*NN + n0 + t] = sd[128 + t] + sd[192 + t];
  }
}

// ---------------------------------------------------------------------------
// K3: MFMA attention, m-split. Block = 32 rows x 1024 cols (half ms); 4 waves =
// 4 k-chunks. B from fragment-ordered hT (coalesced 1KB wave loads). Writes
// UNNORMALIZED f16 acc half + f32 partial psum; consumers normalize.
__global__ void __launch_bounds__(256, 6) k_attn8(const float* __restrict__ src,
                                                  const float* __restrict__ dst,
                                                  const _Float16* __restrict__ hT,
                                                  const u64* __restrict__ maskT,
                                                  _Float16* __restrict__ accB,
                                                  float* __restrict__ psB){
  int ms = blockIdx.x & 1;
  int rb = (blockIdx.x >> 1) & 63;
  int bh = blockIdx.x >> 7;
  int b  = bh >> 2;
  int n0 = rb * 32;
  int t = threadIdx.x;
  int w = t >> 6, l = t & 63;
  int lh = l >> 5, l5 = l & 31;

  __shared__ __align__(16) char smem[9728];    // dstS 4KB in loop; cs 9.2KB epilogue
  __shared__ float rs[4][32];
  __shared__ float red[4];
  float* dstS = (float*)smem;
  float* cs   = (float*)smem;

  {
    const float* dp = dst + bh*NN;
    float4 a = *(const float4*)&dp[t*4];
    float4 bq = *(const float4*)&dp[1024 + t*4];
    float mloc = fmaxf(fmaxf(fmaxf(a.x,a.y), fmaxf(a.z,a.w)),
                       fmaxf(fmaxf(bq.x,bq.y), fmaxf(bq.z,bq.w)));
    *(float4*)&dstS[t*4] = ms ? bq : a;
    #pragma unroll
    for (int o = 32; o >= 1; o >>= 1) mloc = fmaxf(mloc, __shfl_xor(mloc, o));
    if (l == 0) red[w] = mloc;
  }
  __syncthreads();
  float Mbh = fmaxf(fmaxf(red[0], red[1]), fmaxf(red[2], red[3]));
  float srcv = src[bh*NN + n0 + l5];
  float bv = srcv + Mbh;
  float bnd = fmaxf(bv, 0.2f*bv);
  float psum = 0.f;
  f32x16 acc0 = {}, acc1 = {};

  int kb = w*16 + lh*8;
  const u64* mp = maskT + (size_t)(b*32 + ms*16)*NN + n0 + l5;
  const char* gB = (const char*)hT + (size_t)bh*262144 + ms*131072
                   + w*2048 + l5*32 + lh*16;
  u64 mk = *mp;
  f16x8 B0 = *(const f16x8*)gB;
  f16x8 B1 = *(const f16x8*)(gB + 1024);
  float4 dq0 = *(const float4*)&dstS[kb];
  float4 dq1 = *(const float4*)&dstS[kb + 4];

  for (int mt = 0; mt < 16; ++mt){
    u64 mkN = mk; f16x8 B0N = B0, B1N = B1; float4 dq0N = dq0, dq1N = dq1;
    if (mt < 15){
      mp += NN; gB += 8192;
      mkN = *mp;
      B0N = *(const f16x8*)gB;
      B1N = *(const f16x8*)(gB + 1024);
      dq0N = *(const float4*)&dstS[(mt+1)*64 + kb];
      dq1N = *(const float4*)&dstS[(mt+1)*64 + kb + 4];
    }
    unsigned bits = (unsigned)(mk >> kb) & 0xFFu;
    float dvals[8] = {dq0.x,dq0.y,dq0.z,dq0.w,dq1.x,dq1.y,dq1.z,dq1.w};
    f16x8 A;
    #pragma unroll
    for (int i = 0; i < 8; ++i){
      float e = srcv + dvals[i];
      e = fmaxf(e, 0.2f*e);              // leaky (log2-scaled domain)
      e = ((bits >> i) & 1u) ? e : NEGV;
      float p = fexp2(e - bnd);
      psum += p;
      A[i] = (_Float16)p;
    }
    acc0 = __builtin_amdgcn_mfma_f32_32x32x16_f16(A, B0, acc0, 0, 0, 0);
    acc1 = __builtin_amdgcn_mfma_f32_32x32x16_f16(A, B1, acc1, 0, 0, 0);
    mk = mkN; B0 = B0N; B1 = B1N; dq0 = dq0N; dq1 = dq1N;
  }

  psum += __shfl_xor(psum, 32);
  if (l < 32) rs[w][l5] = psum;
  __syncthreads();                       // dstS dead; cs overlay safe
  _Float16* accO = accB + (size_t)ms*2097152;
  float* psO  = psB + (size_t)ms*32768;
  if (t < 32) psO[bh*NN + n0 + t] = rs[0][t] + rs[1][t] + rs[2][t] + rs[3][t];
  // sequential cross-wave combine (fits 9.2KB: 64 lanes x 36 floats)
  #pragma unroll 1
  for (int ww = 1; ww < 4; ++ww){
    if (w == ww){
      float* base = cs + l*36;
      *(f32x16*)(base)      = acc0;
      *(f32x16*)(base + 16) = acc1;
    }
    __syncthreads();
    if (w == 0){
      const float* base = cs + l*36;
      acc0 += *(const f32x16*)(base);
      acc1 += *(const f32x16*)(base + 16);
    }
    __syncthreads();
  }
  if (w == 0){
    #pragma unroll
    for (int g = 0; g < 16; ++g){
      int row = (g & 3) + 8*(g >> 2) + 4*lh;
      size_t o = ((size_t)bh*NN + n0 + row)*DK;
      accO[o + l5]      = (_Float16)acc0[g];
      accO[o + 32 + l5] = (_Float16)acc1[g];
    }
  }
}

// ---------------------------------------------------------------------------
// K4: x[b,j,:] += elu(LN(x1[b,j,:])); x1 = reshape-reinterpret of att1,
// normalization (m-split halves / psum) folded in.
__global__ void __launch_bounds__(256) k_ln1(const _Float16* __restrict__ a0,
                                             const _Float16* __restrict__ a1,
                                             const float* __restrict__ p0,
                                             const float* __restrict__ p1,
                                             const float* __restrict__ sc,
                                             const float* __restrict__ bi,
                                             float* __restrict__ x){
  int j = blockIdx.x & (NN-1);
  int b = blockIdx.x / NN;
  int c = threadIdx.x;
  int w = c >> 6, l = c & 63;
  int hh = j >> 9;
  int node = ((j & 511) << 2) + w;
  size_t ridx = (size_t)(b*NH + hh)*NN + node;
  float inv = 1.f / (p0[ridx] + p1[ridx]);
  size_t idx = ridx*DK + l;
  float v = ((float)a0[idx] + (float)a1[idx]) * inv;
  __shared__ float red[8];
  float s = v;
  #pragma unroll
  for (int o = 32; o >= 1; o >>= 1) s += __shfl_xor(s, o);
  if (l == 0) red[w] = s;
  __syncthreads();
  float mu = (red[0]+red[1]+red[2]+red[3]) * (1.f/HD);
  float dv = v - mu;
  float q = dv*dv;
  #pragma unroll
  for (int o = 32; o >= 1; o >>= 1) q += __shfl_xor(q, o);
  if (l == 0) red[4+w] = q;
  __syncthreads();
  float var = (red[4]+red[5]+red[6]+red[7]) * (1.f/HD);
  float ln = dv * rsqrtf(var + 1e-5f) * sc[c] + bi[c];
  float el = (ln > 0.f) ? ln : (__expf(ln) - 1.f);
  x[(size_t)blockIdx.x*HD + c] += el;
}

// ---------------------------------------------------------------------------
// K5: out[b,n,d] = LN_64( mean_h att2[b,h,n,d] ), normalization folded in
__global__ void __launch_bounds__(256) k_final(const _Float16* __restrict__ a0,
                                               const _Float16* __restrict__ a1,
                                               const float* __restrict__ p0,
                                               const float* __restrict__ p1,
                                               const float* __restrict__ sc,
                                               const float* __restrict__ bi,
                                               float* __restrict__ out){
  int w = threadIdx.x >> 6; int d = threadIdx.x & 63;
  int bn = blockIdx.x*4 + w;
  int b = bn / NN; int n = bn & (NN-1);
  float v = 0.f;
  #pragma unroll
  for (int hh = 0; hh < NH; ++hh){
    size_t ridx = (size_t)(b*NH + hh)*NN + n;
    float inv = 1.f / (p0[ridx] + p1[ridx]);
    size_t idx = ridx*DK + d;
    v += ((float)a0[idx] + (float)a1[idx]) * inv;
  }
  v *= 0.25f;
  float s = v;
  #pragma unroll
  for (int o = 32; o >= 1; o >>= 1) s += __shfl_xor(s, o);
  float mu = s * (1.f/DK);
  float dv = v - mu;
  float q = dv*dv;
  #pragma unroll
  for (int o = 32; o >= 1; o >>= 1) q += __shfl_xor(q, o);
  float var = q * (1.f/DK);
  float ln = dv * rsqrtf(var + 1e-5f) * sc[d] + bi[d];
  out[(size_t)bn*DK + d] = ln;
}

// ---------------------------------------------------------------------------
extern "C" void kernel_launch(void* const* d_in, const int* in_sizes, int n_in,
                              void* d_out, int out_size, void* d_ws, size_t ws_size,
                              hipStream_t stream){
  const float* nf   = (const float*)d_in[0];
  const int*   adj  = (const int*)d_in[1];
  const float* Wp   = (const float*)d_in[2];
  const float* bp   = (const float*)d_in[3];
  const float* W1   = (const float*)d_in[4];
  const float* a1   = (const float*)d_in[5];
  const float* ln1s = (const float*)d_in[6];
  const float* ln1b = (const float*)d_in[7];
  const float* W2   = (const float*)d_in[8];
  const float* a2   = (const float*)d_in[9];
  const float* ln2s = (const float*)d_in[10];
  const float* ln2b = (const float*)d_in[11];

  float* ws   = (float*)d_ws;
  float* x    = ws;                        // 2,097,152 f32
  _Float16* accF = (_Float16*)(ws + 2097152);  // 2 x 2,097,152 f16 = 8 MB
  float* srcb = ws + 3*2097152;            // 32,768
  float* dstb = srcb + 32768;              // 32,768
  float* psA  = dstb + 32768;              // 2 x 32,768
  _Float16* hT = (_Float16*)(psA + 2*32768);  // 2,097,152 f16 = 4 MB
  u64* maskT  = (u64*)(hT + 2097152);      // 262,144 u64 = 2 MB
  _Float16* WT = (_Float16*)(maskT + 262144); // 131,072 f16 = 256 KB
  float* aS   = (float*)(WT + 131072);        // 1024 f32

  _Float16* accH0 = accF;                 // half ms=0
  _Float16* accH1 = accF + 2097152;       // half ms=1
  float* psH0  = psA;
  float* psH1  = psA + 32768;

  k_setup<<<2568,         256, 0, stream>>>(nf, Wp, bp, adj, W1, a1, W2, a2,
                                            x, maskT, WT, aS);
  k_head3<<<BB*NH*NN/64,  256, 0, stream>>>(x, WT,         aS,       hT, srcb, dstb);
  k_attn8<<<BB*NH*NN/16,  256, 0, stream>>>(srcb, dstb, hT, maskT, accF, psA);
  k_ln1  <<<BB*NN,        256, 0, stream>>>(accH0, accH1, psH0, psH1, ln1s, ln1b, x);
  k_head3<<<BB*NH*NN/64,  256, 0, stream>>>(x, WT + 65536, aS + 512, hT, srcb, dstb);
  k_attn8<<<BB*NH*NN/16,  256, 0, stream>>>(srcb, dstb, hT, maskT, accF, psA);
  k_final<<<BB*NN/4,      256, 0, stream>>>(accH0, accH1, psH0, psH1, ln2s, ln2b, (float*)d_out);
}

// Round 12
// 120.096 us; speedup vs baseline: 11.1318x; 1.1458x over previous
//
#include <hip/hip_runtime.h>
#include <hip/hip_bf16.h>
#include <hip/hip_fp16.h>

// Shapes (fixed by the reference)
#define BB   4
#define NN   2048
#define FIN  128
#define HD   256
#define NH   4
#define DK   64
#define NEGV (-1000000000.0f)
#define LOG2E 1.4426950408889634f

typedef _Float16 f16x8 __attribute__((ext_vector_type(8)));
typedef float    f32x16 __attribute__((ext_vector_type(16)));
typedef unsigned long long u64;

// XOR swizzles: flip byte bits 4-6 with row bits (pitch 512B / 256B)
__device__ __forceinline__ int SWZ9(int b){ return b ^ (((b >> 9) & 7) << 4); }
__device__ __forceinline__ int SWZ8(int b){ return b ^ (((b >> 8) & 7) << 4); }

__device__ __forceinline__ float fexp2(float x){
#if __has_builtin(__builtin_amdgcn_exp2f)
  return __builtin_amdgcn_exp2f(x);
#else
  return __exp2f(x);
#endif
}

__device__ __forceinline__ f16x8 pack8(float4 a, float4 b){
  f16x8 r;
  r[0]=(_Float16)a.x; r[1]=(_Float16)a.y; r[2]=(_Float16)a.z; r[3]=(_Float16)a.w;
  r[4]=(_Float16)b.x; r[5]=(_Float16)b.y; r[6]=(_Float16)b.z; r[7]=(_Float16)b.w;
  return r;
}

// ---------------------------------------------------------------------------
// K_setup: blocks [0,2048): int4-wide bitmask pack (maskT[b][mt][n]).
//          blocks [2048,2056): WTF fragment-ordered head weights + aS.
//          blocks [2056,2064): WpF fragment-ordered proj weights.
// Fragment layout (1KB each): lane(l5,lh) reads 16B at l5*32+lh*16; f16 index
// j = l5*16+lh*8+e holds element (k = kk*16+lh*8+e, col = base+l5).
__global__ void __launch_bounds__(256) k_setup(const int* __restrict__ adj,
                                               const float* __restrict__ Wp,
                                               const float* __restrict__ W1,
                                               const float* __restrict__ a1,
                                               const float* __restrict__ W2,
                                               const float* __restrict__ a2,
                                               u64* __restrict__ maskT,
                                               _Float16* __restrict__ WTF,
                                               _Float16* __restrict__ WpF,
                                               float* __restrict__ aS){
  int bid = blockIdx.x;
  int t = threadIdx.x;
  if (bid < 2048){
    int w = t >> 6, lane = t & 63;
    int row = bid*4 + w;
    int b = row >> 11, n = row & (NN-1);
    const int4* ar = (const int4*)(adj + (size_t)row*NN);
    int g = lane >> 4, q = lane & 15;
    #pragma unroll 2
    for (int step = 0; step < 8; ++step){
      int4 v = ar[step*64 + lane];
      unsigned nib = (unsigned)((v.x!=0) | ((v.y!=0)<<1) | ((v.z!=0)<<2) | ((v.w!=0)<<3));
      unsigned lo = (q < 8) ? (nib << (q*4)) : 0u;
      unsigned hi = (q < 8) ? 0u : (nib << ((q-8)*4));
      #pragma unroll
      for (int off = 1; off < 16; off <<= 1){
        lo |= __shfl_xor(lo, off);
        hi |= __shfl_xor(hi, off);
      }
      if (q == 0) maskT[(size_t)(b*32 + step*4 + g)*NN + n] = ((u64)hi << 32) | lo;
    }
  } else if (bid < 2056){
    int qq = bid - 2048;            // lay*4+hh
    int lay = qq >> 2, hh = qq & 3;
    const float* W = (lay ? W2 : W1) + (size_t)hh*HD*DK;
    const float* a = (lay ? a2 : a1) + (size_t)hh*2*DK;
    _Float16* wf = WTF + (size_t)qq*32*512;     // 32 frags x 512 f16
    int j = t*2;
    int l5 = j >> 4, lh = (j >> 3) & 1, e = j & 7;
    #pragma unroll 4
    for (int f = 0; f < 32; ++f){
      int kk = f >> 1, dh = f & 1;
      wf[f*512 + j]     = (_Float16)W[(kk*16 + lh*8 + e    )*DK + dh*32 + l5];
      wf[f*512 + j + 1] = (_Float16)W[(kk*16 + lh*8 + e + 1)*DK + dh*32 + l5];
    }
    if (t < 128) aS[(size_t)qq*128 + t] = a[t] * LOG2E;
  } else {
    int kk = bid - 2056;            // 0..7 (k-step)
    int j = t*2;
    int l5 = j >> 4, lh = (j >> 3) & 1, e = j & 7;
    #pragma unroll 4
    for (int cs = 0; cs < 8; ++cs){
      WpF[(kk*8 + cs)*512 + j]     = (_Float16)Wp[(kk*16 + lh*8 + e    )*HD + cs*32 + l5];
      WpF[(kk*8 + cs)*512 + j + 1] = (_Float16)Wp[(kk*16 + lh*8 + e + 1)*HD + cs*32 + l5];
    }
  }
}

// ---------------------------------------------------------------------------
// K2: MFMA head projection, proj-fused for layer 1.
template<int L1>
__global__ void __launch_bounds__(256) k_head4(const float* __restrict__ xin,
                                               const _Float16* __restrict__ WpF,
                                               const _Float16* __restrict__ WTF,
                                               const float* __restrict__ aS,
                                               const float* __restrict__ bp,
                                               float* __restrict__ xout,
                                               _Float16* __restrict__ hT,
                                               float* __restrict__ src,
                                               float* __restrict__ dst){
  int nt = blockIdx.x & 31;
  int bh = blockIdx.x >> 5;
  int b = bh >> 2, hh = bh & 3;
  int n0 = nt * 64;
  int t = threadIdx.x;
  int w = t >> 6, l = t & 63, lh = l >> 5, l5 = l & 31;
  int wr = w >> 1, wc = w & 1;

  __shared__ __align__(16) char sm[50176];  // xs16 [0,32K); nfs [32K,48K); sd [48K,49K)

  if (L1){
    // stage nf tile 64x128 -> f16 swizzled at +32768 (256B pitch)
    {
      int r = t >> 2, c0 = (t & 3) * 32;
      const float* np = xin + ((size_t)(b*NN) + n0 + r)*FIN + c0;
      #pragma unroll
      for (int u = 0; u < 4; ++u){
        float4 v0 = *(const float4*)&np[u*8];
        float4 v1 = *(const float4*)&np[u*8 + 4];
        *(f16x8*)&sm[32768 + SWZ8(r*256 + (c0 + u*8)*2)] = pack8(v0, v1);
      }
    }
    __syncthreads();
    // proj MFMA: wave w -> cols w*64..+63; rows 2 subtiles of 32; K=128
    f32x16 p00 = {}, p01 = {}, p10 = {}, p11 = {};
    #pragma unroll
    for (int kk = 0; kk < 8; ++kk){
      int ab = (kk*16 + lh*8)*2;
      f16x8 A0 = *(const f16x8*)&sm[32768 + SWZ8(l5*256 + ab)];
      f16x8 A1 = *(const f16x8*)&sm[32768 + SWZ8((32 + l5)*256 + ab)];
      const char* bf = (const char*)WpF + (size_t)(kk*8 + w*2)*1024 + l5*32 + lh*16;
      f16x8 B0 = *(const f16x8*)bf;
      f16x8 B1 = *(const f16x8*)(bf + 1024);
      p00 = __builtin_amdgcn_mfma_f32_32x32x16_f16(A0, B0, p00, 0, 0, 0);
      p01 = __builtin_amdgcn_mfma_f32_32x32x16_f16(A0, B1, p01, 0, 0, 0);
      p10 = __builtin_amdgcn_mfma_f32_32x32x16_f16(A1, B0, p10, 0, 0, 0);
      p11 = __builtin_amdgcn_mfma_f32_32x32x16_f16(A1, B1, p11, 0, 0, 0);
    }
    // add bias, scatter to x f32 (hh==0 blocks) + f16 x-tile (xs16)
    int c0a = w*64 + l5;
    float bp0 = bp[c0a], bp1 = bp[c0a + 32];
    size_t ro = ((size_t)(b*NN) + n0)*HD;
    #pragma unroll
    for (int g = 0; g < 16; ++g){
      int rr = (g & 3) + 8*(g >> 2) + 4*lh;
      float v00 = p00[g] + bp0, v01 = p01[g] + bp1;
      float v10 = p10[g] + bp0, v11 = p11[g] + bp1;
      *(_Float16*)&sm[SWZ9(rr*512 + c0a*2)]             = (_Float16)v00;
      *(_Float16*)&sm[SWZ9(rr*512 + (c0a + 32)*2)]      = (_Float16)v01;
      *(_Float16*)&sm[SWZ9((rr+32)*512 + c0a*2)]        = (_Float16)v10;
      *(_Float16*)&sm[SWZ9((rr+32)*512 + (c0a + 32)*2)] = (_Float16)v11;
      if (hh == 0){
        xout[ro + (size_t)rr*HD + c0a]           = v00;
        xout[ro + (size_t)rr*HD + c0a + 32]      = v01;
        xout[ro + (size_t)(rr+32)*HD + c0a]      = v10;
        xout[ro + (size_t)(rr+32)*HD + c0a + 32] = v11;
      }
    }
    __syncthreads();
  } else {
    int r = t >> 2, ks = (t & 3) * 64;
    const float* xp = &xin[((size_t)(b*NN) + n0 + r)*HD + ks];
    #pragma unroll
    for (int u = 0; u < 8; ++u){
      float4 v0 = *(const float4*)&xp[u*8];
      float4 v1 = *(const float4*)&xp[u*8 + 4];
      *(f16x8*)&sm[SWZ9(r*512 + (ks + u*8)*2)] = pack8(v0, v1);
    }
    __syncthreads();
  }

  // h-MFMA: A = x-tile rows (wr half), B = WTF frags (wc d-half), K=256
  f32x16 hA = {}, hB = {};
  const char* wtb = (const char*)WTF + (size_t)hh*32768 + wc*1024 + l5*32 + lh*16;
  #pragma unroll
  for (int kk = 0; kk < 16; kk += 2){
    int ab0 = (kk*16 + lh*8)*2;
    int ab1 = ((kk+1)*16 + lh*8)*2;
    f16x8 A0 = *(const f16x8*)&sm[SWZ9((wr*32 + l5)*512 + ab0)];
    f16x8 A1 = *(const f16x8*)&sm[SWZ9((wr*32 + l5)*512 + ab1)];
    f16x8 B0 = *(const f16x8*)(wtb + (size_t)kk*2048);
    f16x8 B1 = *(const f16x8*)(wtb + (size_t)(kk+1)*2048);
    hA = __builtin_amdgcn_mfma_f32_32x32x16_f16(A0, B0, hA, 0, 0, 0);
    hB = __builtin_amdgcn_mfma_f32_32x32x16_f16(A1, B1, hB, 0, 0, 0);
  }
  f32x16 acc = hA + hB;

  __syncthreads();   // xs16 dead; overlay ls
  _Float16* ls = (_Float16*)sm;        // [64 d][80 rows pad] f16 = 10240B
  int col = wc*32 + l5;
  float as = aS[(size_t)hh*128 + col];
  float ad = aS[(size_t)hh*128 + 64 + col];
  float* sd = (float*)(sm + 49152);    // [2][2][64] f32
  #pragma unroll
  for (int g = 0; g < 16; ++g){
    int row = wr*32 + (g & 3) + 8*(g >> 2) + 4*lh;
    ls[col*80 + row] = (_Float16)acc[g];
    float sv = acc[g] * as;
    float dv = acc[g] * ad;
    #pragma unroll
    for (int o = 16; o >= 1; o >>= 1){ sv += __shfl_xor(sv, o); dv += __shfl_xor(dv, o); }
    if (l5 == 0){
      sd[wc*64 + row]       = sv;
      sd[128 + wc*64 + row] = dv;
    }
  }
  __syncthreads();
  int dd = t >> 2, part = t & 3;
  f16x8 o0 = *(const f16x8*)&ls[dd*80 + part*16];
  f16x8 o1 = *(const f16x8*)&ls[dd*80 + part*16 + 8];
  int base = part*1024 + (dd >> 5)*512 + (dd & 31)*16;
  _Float16* op = hT + (size_t)bh*131072 + (size_t)nt*4096 + base;
  *(f16x8*)op = o0;
  *(f16x8*)(op + 8) = o1;
  if (t < 64){
    src[bh*NN + n0 + t] = sd[t] + sd[64 + t];
    dst[bh*NN + n0 + t] = sd[128 + t] + sd[192 + t];
  }
}

// ---------------------------------------------------------------------------
// K3: MFMA attention, m-split (unchanged from round 11).
__global__ void __launch_bounds__(256, 6) k_attn8(const float* __restrict__ src,
                                                  const float* __restrict__ dst,
                                                  const _Float16* __restrict__ hT,
                                                  const u64* __restrict__ maskT,
                                                  _Float16* __restrict__ accB,
                                                  float* __restrict__ psB){
  int ms = blockIdx.x & 1;
  int rb = (blockIdx.x >> 1) & 63;
  int bh = blockIdx.x >> 7;
  int b  = bh >> 2;
  int n0 = rb * 32;
  int t = threadIdx.x;
  int w = t >> 6, l = t & 63;
  int lh = l >> 5, l5 = l & 31;

  __shared__ __align__(16) char smem[9728];
  __shared__ float rs[4][32];
  __shared__ float red[4];
  float* dstS = (float*)smem;
  float* cs   = (float*)smem;

  {
    const float* dp = dst + bh*NN;
    float4 a = *(const float4*)&dp[t*4];
    float4 bq = *(const float4*)&dp[1024 + t*4];
    float mloc = fmaxf(fmaxf(fmaxf(a.x,a.y), fmaxf(a.z,a.w)),
                       fmaxf(fmaxf(bq.x,bq.y), fmaxf(bq.z,bq.w)));
    *(float4*)&dstS[t*4] = ms ? bq : a;
    #pragma unroll
    for (int o = 32; o >= 1; o >>= 1) mloc = fmaxf(mloc, __shfl_xor(mloc, o));
    if (l == 0) red[w] = mloc;
  }
  __syncthreads();
  float Mbh = fmaxf(fmaxf(red[0], red[1]), fmaxf(red[2], red[3]));
  float srcv = src[bh*NN + n0 + l5];
  float bv = srcv + Mbh;
  float bnd = fmaxf(bv, 0.2f*bv);
  float psum = 0.f;
  f32x16 acc0 = {}, acc1 = {};

  int kb = w*16 + lh*8;
  const u64* mp = maskT + (size_t)(b*32 + ms*16)*NN + n0 + l5;
  const char* gB = (const char*)hT + (size_t)bh*262144 + ms*131072
                   + w*2048 + l5*32 + lh*16;
  u64 mk = *mp;
  f16x8 B0 = *(const f16x8*)gB;
  f16x8 B1 = *(const f16x8*)(gB + 1024);
  float4 dq0 = *(const float4*)&dstS[kb];
  float4 dq1 = *(const float4*)&dstS[kb + 4];

  for (int mt = 0; mt < 16; ++mt){
    u64 mkN = mk; f16x8 B0N = B0, B1N = B1; float4 dq0N = dq0, dq1N = dq1;
    if (mt < 15){
      mp += NN; gB += 8192;
      mkN = *mp;
      B0N = *(const f16x8*)gB;
      B1N = *(const f16x8*)(gB + 1024);
      dq0N = *(const float4*)&dstS[(mt+1)*64 + kb];
      dq1N = *(const float4*)&dstS[(mt+1)*64 + kb + 4];
    }
    unsigned bits = (unsigned)(mk >> kb) & 0xFFu;
    float dvals[8] = {dq0.x,dq0.y,dq0.z,dq0.w,dq1.x,dq1.y,dq1.z,dq1.w};
    f16x8 A;
    #pragma unroll
    for (int i = 0; i < 8; ++i){
      float e = srcv + dvals[i];
      e = fmaxf(e, 0.2f*e);              // leaky (log2-scaled domain)
      e = ((bits >> i) & 1u) ? e : NEGV;
      float p = fexp2(e - bnd);
      psum += p;
      A[i] = (_Float16)p;
    }
    acc0 = __builtin_amdgcn_mfma_f32_32x32x16_f16(A, B0, acc0, 0, 0, 0);
    acc1 = __builtin_amdgcn_mfma_f32_32x32x16_f16(A, B1, acc1, 0, 0, 0);
    mk = mkN; B0 = B0N; B1 = B1N; dq0 = dq0N; dq1 = dq1N;
  }

  psum += __shfl_xor(psum, 32);
  if (l < 32) rs[w][l5] = psum;
  __syncthreads();
  _Float16* accO = accB + (size_t)ms*2097152;
  float* psO  = psB + (size_t)ms*32768;
  if (t < 32) psO[bh*NN + n0 + t] = rs[0][t] + rs[1][t] + rs[2][t] + rs[3][t];
  #pragma unroll 1
  for (int ww = 1; ww < 4; ++ww){
    if (w == ww){
      float* base = cs + l*36;
      *(f32x16*)(base)      = acc0;
      *(f32x16*)(base + 16) = acc1;
    }
    __syncthreads();
    if (w == 0){
      const float* base = cs + l*36;
      acc0 += *(const f32x16*)(base);
      acc1 += *(const f32x16*)(base + 16);
    }
    __syncthreads();
  }
  if (w == 0){
    #pragma unroll
    for (int g = 0; g < 16; ++g){
      int row = (g & 3) + 8*(g >> 2) + 4*lh;
      size_t o = ((size_t)bh*NN + n0 + row)*DK;
      accO[o + l5]      = (_Float16)acc0[g];
      accO[o + 32 + l5] = (_Float16)acc1[g];
    }
  }
}

// ---------------------------------------------------------------------------
// K4: x[b,j,:] += elu(LN(x1[b,j,:])); normalization folded in.
__global__ void __launch_bounds__(256) k_ln1(const _Float16* __restrict__ a0,
                                             const _Float16* __restrict__ a1,
                                             const float* __restrict__ p0,
                                             const float* __restrict__ p1,
                                             const float* __restrict__ sc,
                                             const float* __restrict__ bi,
                                             float* __restrict__ x){
  int j = blockIdx.x & (NN-1);
  int b = blockIdx.x / NN;
  int c = threadIdx.x;
  int w = c >> 6, l = c & 63;
  int hh = j >> 9;
  int node = ((j & 511) << 2) + w;
  size_t ridx = (size_t)(b*NH + hh)*NN + node;
  float inv = 1.f / (p0[ridx] + p1[ridx]);
  size_t idx = ridx*DK + l;
  float v = ((float)a0[idx] + (float)a1[idx]) * inv;
  __shared__ float red[8];
  float s = v;
  #pragma unroll
  for (int o = 32; o >= 1; o >>= 1) s += __shfl_xor(s, o);
  if (l == 0) red[w] = s;
  __syncthreads();
  float mu = (red[0]+red[1]+red[2]+red[3]) * (1.f/HD);
  float dv = v - mu;
  float q = dv*dv;
  #pragma unroll
  for (int o = 32; o >= 1; o >>= 1) q += __shfl_xor(q, o);
  if (l == 0) red[4+w] = q;
  __syncthreads();
  float var = (red[4]+red[5]+red[6]+red[7]) * (1.f/HD);
  float ln = dv * rsqrtf(var + 1e-5f) * sc[c] + bi[c];
  float el = (ln > 0.f) ? ln : (__expf(ln) - 1.f);
  x[(size_t)blockIdx.x*HD + c] += el;
}

// ---------------------------------------------------------------------------
// K5: out[b,n,d] = LN_64( mean_h att2[b,h,n,d] ), normalization folded in
__global__ void __launch_bounds__(256) k_final(const _Float16* __restrict__ a0,
                                               const _Float16* __restrict__ a1,
                                               const float* __restrict__ p0,
                                               const float* __restrict__ p1,
                                               const float* __restrict__ sc,
                                               const float* __restrict__ bi,
                                               float* __restrict__ out){
  int w = threadIdx.x >> 6; int d = threadIdx.x & 63;
  int bn = blockIdx.x*4 + w;
  int b = bn / NN; int n = bn & (NN-1);
  float v = 0.f;
  #pragma unroll
  for (int hh = 0; hh < NH; ++hh){
    size_t ridx = (size_t)(b*NH + hh)*NN + n;
    float inv = 1.f / (p0[ridx] + p1[ridx]);
    size_t idx = ridx*DK + d;
    v += ((float)a0[idx] + (float)a1[idx]) * inv;
  }
  v *= 0.25f;
  float s = v;
  #pragma unroll
  for (int o = 32; o >= 1; o >>= 1) s += __shfl_xor(s, o);
  float mu = s * (1.f/DK);
  float dv = v - mu;
  float q = dv*dv;
  #pragma unroll
  for (int o = 32; o >= 1; o >>= 1) q += __shfl_xor(q, o);
  float var = q * (1.f/DK);
  float ln = dv * rsqrtf(var + 1e-5f) * sc[d] + bi[d];
  out[(size_t)bn*DK + d] = ln;
}

// ---------------------------------------------------------------------------
extern "C" void kernel_launch(void* const* d_in, const int* in_sizes, int n_in,
                              void* d_out, int out_size, void* d_ws, size_t ws_size,
                              hipStream_t stream){
  const float* nf   = (const float*)d_in[0];
  const int*   adj  = (const int*)d_in[1];
  const float* Wp   = (const float*)d_in[2];
  const float* bp   = (const float*)d_in[3];
  const float* W1   = (const float*)d_in[4];
  const float* a1   = (const float*)d_in[5];
  const float* ln1s = (const float*)d_in[6];
  const float* ln1b = (const float*)d_in[7];
  const float* W2   = (const float*)d_in[8];
  const float* a2   = (const float*)d_in[9];
  const float* ln2s = (const float*)d_in[10];
  const float* ln2b = (const float*)d_in[11];

  float* ws   = (float*)d_ws;
  float* x    = ws;                            // 2,097,152 f32
  _Float16* accF = (_Float16*)(ws + 2097152);  // 2 x 2,097,152 f16
  float* srcb = ws + 3*2097152;                // 32,768
  float* dstb = srcb + 32768;                  // 32,768
  float* psA  = dstb + 32768;                  // 2 x 32,768
  _Float16* hT = (_Float16*)(psA + 2*32768);   // 2,097,152 f16
  u64* maskT  = (u64*)(hT + 2097152);          // 262,144 u64
  _Float16* WTF = (_Float16*)(maskT + 262144); // 131,072 f16 (2 layers)
  _Float16* WpF = WTF + 131072;                // 32,768 f16
  float* aS   = (float*)(WpF + 32768);         // 1024 f32

  _Float16* accH0 = accF;
  _Float16* accH1 = accF + 2097152;
  float* psH0  = psA;
  float* psH1  = psA + 32768;

  k_setup   <<<2064,        256, 0, stream>>>(adj, Wp, W1, a1, W2, a2,
                                              maskT, WTF, WpF, aS);
  k_head4<1><<<BB*NH*NN/64, 256, 0, stream>>>(nf, WpF, WTF,        aS,       bp, x, hT, srcb, dstb);
  k_attn8   <<<BB*NH*NN/16, 256, 0, stream>>>(srcb, dstb, hT, maskT, accF, psA);
  k_ln1     <<<BB*NN,       256, 0, stream>>>(accH0, accH1, psH0, psH1, ln1s, ln1b, x);
  k_head4<0><<<BB*NH*NN/64, 256, 0, stream>>>(x, WpF, WTF + 65536, aS + 512, bp, x, hT, srcb, dstb);
  k_attn8   <<<BB*NH*NN/16, 256, 0, stream>>>(srcb, dstb, hT, maskT, accF, psA);
  k_final   <<<BB*NN/4,     256, 0, stream>>>(accH0, accH1, psH0, psH1, ln2s, ln2b, (float*)d_out);
}